// Round 11
// baseline (390.335 us; speedup 1.0000x reference)
//
#include <hip/hip_runtime.h>

#define TT 16
#define CC 320
#define NHEADS 8
#define DH 64
#define INNER 512

typedef float f32x4 __attribute__((ext_vector_type(4)));
typedef float f32x16 __attribute__((ext_vector_type(16)));
typedef short bf16x8 __attribute__((ext_vector_type(8)));
typedef unsigned short u16;

#define Z16 {0.f,0.f,0.f,0.f,0.f,0.f,0.f,0.f,0.f,0.f,0.f,0.f,0.f,0.f,0.f,0.f}

__device__ __forceinline__ float bf2f(u16 u){
    union { unsigned int i; float f; } v; v.i = ((unsigned int)u) << 16; return v.f;
}
__device__ __forceinline__ u16 f2bf(float f){
    union { float f; unsigned int i; } v; v.f = f;
    unsigned int x = v.i;
    return (u16)((x + 0x7fffu + ((x >> 16) & 1u)) >> 16);   // RNE
}

// ---------------- kernel 1a: Wq/Wk/Wv fp32 -> bf16 32x32x16-frag, 12KB-CHUNK-major ----------------
// frag f = ((hd*10 + c)*6 + nblk)*2 + kl ; kk = c*2 + kl (K-step 16)
// nblk 0,1=Q  2,3=K  4,5=V (32 cols each). Within frag: lane = ((k%16)>>3)*32 + (n%32), elem=k%8.
__global__ __launch_bounds__(256) void k_wqkv32(const float* __restrict__ wq, const float* __restrict__ wk,
                                                const float* __restrict__ wv, u16* __restrict__ dst){
    int gid  = blockIdx.x * 256 + threadIdx.x;   // 0..61439
    int lane = gid & 63;
    int f    = gid >> 6;                          // 0..959
    int local = f % 12;
    int kl   = local & 1;
    int nblk = local >> 1;
    int c    = (f / 12) % 10;
    int hd   = f / 120;
    int kk   = c * 2 + kl;
    const float* W = (nblk < 2) ? wq : (nblk < 4) ? wk : wv;
    int n  = hd * DH + (nblk & 1) * 32 + (lane & 31);
    int k0 = kk * 16 + (lane >> 5) * 8;
    const float* src = W + (size_t)n * CC + k0;
    f32x4 v0 = *(const f32x4*)src;
    f32x4 v1 = *(const f32x4*)(src + 4);
    bf16x8 o;
    o[0] = (short)f2bf(v0[0]); o[1] = (short)f2bf(v0[1]);
    o[2] = (short)f2bf(v0[2]); o[3] = (short)f2bf(v0[3]);
    o[4] = (short)f2bf(v1[0]); o[5] = (short)f2bf(v1[1]);
    o[6] = (short)f2bf(v1[2]); o[7] = (short)f2bf(v1[3]);
    *(bf16x8*)(dst + (size_t)gid * 8) = o;
}

// ---------------- kernel 1b: Wo fp32 -> bf16 32x32x16-frag-major ----------------
// frag f = nb*32 + kt (nb 0..9 n-blocks of 32, kt 0..31 k-tiles of 16).
// Within frag: lane = ((k%16)>>3)*32 + (n%32), elem = k%8.
__global__ __launch_bounds__(256) void k_wo32(const float* __restrict__ wo, u16* __restrict__ dst){
    int gid  = blockIdx.x * 256 + threadIdx.x;   // 0..20479
    int lane = gid & 63;
    int f    = gid >> 6;                          // 0..319
    int kt   = f & 31;
    int nb   = f >> 5;
    int n  = nb * 32 + (lane & 31);
    int k0 = kt * 16 + (lane >> 5) * 8;
    const float* src = wo + (size_t)n * INNER + k0;
    f32x4 v0 = *(const f32x4*)src;
    f32x4 v1 = *(const f32x4*)(src + 4);
    bf16x8 o;
    o[0] = (short)f2bf(v0[0]); o[1] = (short)f2bf(v0[1]);
    o[2] = (short)f2bf(v0[2]); o[3] = (short)f2bf(v0[3]);
    o[4] = (short)f2bf(v1[0]); o[5] = (short)f2bf(v1[1]);
    o[6] = (short)f2bf(v1[2]); o[7] = (short)f2bf(v1[3]);
    *(bf16x8*)(dst + (size_t)gid * 8) = o;
}

// ---------------- kernel 2: transpose + LayerNorm -> xn bf16 32x32x16 A-frag-major ----------------
__global__ __launch_bounds__(256) void k_ln(const float* __restrict__ x, const float* __restrict__ lnw,
                                            const float* __restrict__ lnb, u16* __restrict__ xnf){
    __shared__ float tile[CC][37];
    __shared__ float psum[32][36];
    __shared__ float psq[32][36];
    __shared__ float meanb[32];
    __shared__ float rstdb[32];

    int wg = blockIdx.x;                 // (b,h,t)
    int t = wg & 15, h = (wg >> 4) & 31, b = wg >> 9;
    int tid = threadIdx.x;
    const size_t base = ((size_t)(b * CC) * TT + t) * 1024 + h * 32;

    int w4 = (tid & 7) * 4, cg = tid >> 3;
    f32x4 s4 = {0.f,0.f,0.f,0.f}, q4 = {0.f,0.f,0.f,0.f};
    for (int i = 0; i < 10; ++i){
        int c = cg * 10 + i;
        f32x4 v = *(const f32x4*)(x + base + (size_t)c * 16384 + w4);
        tile[c][w4 + 0] = v[0]; tile[c][w4 + 1] = v[1];
        tile[c][w4 + 2] = v[2]; tile[c][w4 + 3] = v[3];
        s4 += v; q4 += v * v;
    }
    psum[cg][w4 + 0] = s4[0]; psum[cg][w4 + 1] = s4[1]; psum[cg][w4 + 2] = s4[2]; psum[cg][w4 + 3] = s4[3];
    psq [cg][w4 + 0] = q4[0]; psq [cg][w4 + 1] = q4[1]; psq [cg][w4 + 2] = q4[2]; psq [cg][w4 + 3] = q4[3];
    __syncthreads();

    if (tid < 32){
        float s = 0.f, q = 0.f;
        for (int g = 0; g < 32; ++g){ s += psum[g][tid]; q += psq[g][tid]; }
        float mean = s * (1.f / CC);
        float var  = q * (1.f / CC) - mean * mean;
        meanb[tid] = mean;
        rstdb[tid] = rsqrtf(var + 1e-5f);
    }
    __syncthreads();

    int cl = tid & 63, wq_ = tid >> 6;
    float lw[5], lb[5];
    #pragma unroll
    for (int ci = 0; ci < 5; ++ci){ lw[ci] = lnw[ci * 64 + cl]; lb[ci] = lnb[ci * 64 + cl]; }
    int s_base = (b * 32 + h) * 32;
    for (int wi = 0; wi < 8; ++wi){
        int w = wq_ * 8 + wi;
        float mean = meanb[w], rstd = rstdb[w];
        int s = s_base + w;
        int row = ((s & 1) << 4) | t;
        size_t m32 = (size_t)(s >> 1);
        #pragma unroll
        for (int ci = 0; ci < 5; ++ci){
            int c = ci * 64 + cl;
            float nv = (tile[c][w] - mean) * rstd * lw[ci] + lb[ci];
            int lane = ((((c & 15) >> 3)) << 5) | row;
            xnf[((m32 * 20 + (c >> 4)) * 64 + lane) * 8 + (c & 7)] = f2bf(nv);
        }
    }
}

// ---------------- kernel 3: fused QKV + attention + O-proj, LDS-staged weights ----------------
// R8-exact schedule (double-buffer, vmcnt(0) drain, 2 barriers/chunk). Math verbatim R8.
// NEW: per-head O-proj accumulation (40 mfma32/wave/head; A = attn-out from wave-private
// KH, B = Wo 32x32-frags from L2 — identical addresses across waves, no extra barriers).
// Epilogue writes proj + bias directly; ao buffer and k_oproj eliminated.
#define QH(w,s,r,c) smem[((((w)*2+(s))*16+(r))*72) + (c)]
#define KH(w,s,r,c) smem[9216 + ((((w)*2+(s))*16+(r))*72) + (c)]
#define VT(w,s,d,k) smem[18432 + ((((w)*2+(s))*64+(d))*36) + (k)]

__global__ __attribute__((amdgpu_flat_work_group_size(256, 256), amdgpu_waves_per_eu(2, 2)))
void k_attn(const u16* __restrict__ xnf,
            const u16* __restrict__ wqkv,
            const u16* __restrict__ wof,
            const float* __restrict__ bo,
            u16* __restrict__ proj){
    // u16 indices: qh [0,9216) kh [9216,18432) vt [18432,36864)  (73,728 B total)
    // weight buffers overlay: buf0 = [0,6144), buf1 = [6144,12288)  (12KB each)
    __shared__ u16 smem[36864];

    const int tid  = threadIdx.x;
    const int lane = tid & 63;
    const int wid  = tid >> 6;        // 0..3
    const int l31  = lane & 31;
    const int h32  = lane >> 5;
    const int l15  = lane & 15;
    const int g4   = lane >> 4;
    const int m32  = blockIdx.x * 4 + wid;
    const f32x4 zero4 = {0.f, 0.f, 0.f, 0.f};

    // zero vt pad cols 16..31 once (vt region is never overlaid; per-head writes touch cols 0..15 only)
    #pragma unroll
    for (int j = 0; j < 32; ++j){
        int idx = j * 64 + lane;           // 0..2047 per wave slice
        int smp = idx >> 10;
        int d   = (idx >> 4) & 63;
        VT(wid, smp, d, 16 + (idx & 15)) = 0;
    }

    // persistent A-frags (this wave's 32 rows x 320 K), coalesced frag loads
    bf16x8 a_f[20];
    {
        const u16* xp = xnf + ((size_t)m32 * 20 * 64 + lane) * 8;
        #pragma unroll
        for (int kk = 0; kk < 20; ++kk)
            a_f[kk] = *(const bf16x8*)(xp + kk * 512);
    }

    // per-lane bias for the 10 O-proj n-blocks
    float bias[10];
    #pragma unroll
    for (int nb = 0; nb < 10; ++nb) bias[nb] = bo[nb * 32 + l31];

    // persistent O-proj accumulators: 10 n-blocks x (32 rows x 32 cols)
    f32x16 acco[10];
    #pragma unroll
    for (int nb = 0; nb < 10; ++nb) acco[nb] = (f32x16)Z16;

    #define STAGE(hd_, c_) do {                                                        \
        const u16* gsrc_ = wqkv + ((size_t)((hd_) * 10 + (c_)) * 6144);                \
        u16* ldst_ = (u16*)smem + ((c_) & 1) * 6144;                                   \
        _Pragma("unroll")                                                              \
        for (int i_ = 0; i_ < 3; ++i_)                                                 \
            __builtin_amdgcn_global_load_lds(                                          \
                (const __attribute__((address_space(1))) void*)(gsrc_ + (tid + i_ * 256) * 8), \
                (__attribute__((address_space(3))) void*)(ldst_ + (tid + i_ * 256) * 8),       \
                16, 0, 0);                                                             \
    } while (0)

    for (int hd = 0; hd < NHEADS; ++hd){
        // all waves done with prev head's qh/kh reads before staging clobbers them
        __builtin_amdgcn_sched_barrier(0);
        __builtin_amdgcn_s_barrier();
        __builtin_amdgcn_sched_barrier(0);

        STAGE(hd, 0);

        f32x16 acc[6];
        #pragma unroll
        for (int nb = 0; nb < 6; ++nb) acc[nb] = (f32x16)Z16;

        #pragma unroll
        for (int c = 0; c < 10; ++c){
            asm volatile("s_waitcnt vmcnt(0)" ::: "memory");
            __builtin_amdgcn_sched_barrier(0);
            __builtin_amdgcn_s_barrier();      // chunk c visible to all waves
            __builtin_amdgcn_sched_barrier(0);
            if (c < 9) STAGE(hd, c + 1);       // prefetch next chunk during compute
            const u16* wb = (const u16*)smem + (c & 1) * 6144;
            #pragma unroll
            for (int kl = 0; kl < 2; ++kl){
                #pragma unroll
                for (int nb = 0; nb < 6; ++nb){
                    bf16x8 b = *(const bf16x8*)(wb + (nb * 2 + kl) * 512 + lane * 8);
                    acc[nb] = __builtin_amdgcn_mfma_f32_32x32x16_bf16(a_f[c * 2 + kl], b, acc[nb], 0, 0, 0);
                }
            }
            __builtin_amdgcn_sched_barrier(0);
            __builtin_amdgcn_s_barrier();      // all waves done reading buf[c&1]
            __builtin_amdgcn_sched_barrier(0);
        }

        // ---- unpack QKV accumulators to wave-private LDS slices ----
        #pragma unroll
        for (int r = 0; r < 16; ++r){
            int row = (r & 3) + 8 * (r >> 2) + 4 * h32;   // verified 32x32 C layout
            int smp = row >> 4, tr = row & 15;
            QH(wid, smp, tr, l31)      = f2bf(acc[0][r] * 0.125f);   // pre-scale 1/sqrt(64)
            QH(wid, smp, tr, 32 + l31) = f2bf(acc[1][r] * 0.125f);
            KH(wid, smp, tr, l31)      = f2bf(acc[2][r]);
            KH(wid, smp, tr, 32 + l31) = f2bf(acc[3][r]);
            VT(wid, smp, l31, tr)      = f2bf(acc[4][r]);            // V^T: [d][key16]
            VT(wid, smp, 32 + l31, tr) = f2bf(acc[5][r]);
        }

        // ---- attention, per owned sample (wave-private); attn-out -> KH rows ----
        #pragma unroll
        for (int smp = 0; smp < 2; ++smp){
            f32x4 sc = zero4;
            #pragma unroll
            for (int k0 = 0; k0 < DH; k0 += 32){
                bf16x8 qa = *(const bf16x8*)&QH(wid, smp, l15, k0 + g4 * 8);
                bf16x8 kb = *(const bf16x8*)&KH(wid, smp, l15, k0 + g4 * 8);
                sc = __builtin_amdgcn_mfma_f32_16x16x32_bf16(qa, kb, sc, 0, 0, 0);
            }
            f32x4 pr;
            #pragma unroll
            for (int r = 0; r < 4; ++r){
                float m = sc[r];
                m = fmaxf(m, __shfl_xor(m, 1)); m = fmaxf(m, __shfl_xor(m, 2));
                m = fmaxf(m, __shfl_xor(m, 4)); m = fmaxf(m, __shfl_xor(m, 8));
                float e = __expf(sc[r] - m);
                float ss = e;
                ss += __shfl_xor(ss, 1); ss += __shfl_xor(ss, 2);
                ss += __shfl_xor(ss, 4); ss += __shfl_xor(ss, 8);
                pr[r] = e / ss;
            }
            // P -> qh cols 0..31 (Q dead); keys 16..31 zero
            #pragma unroll
            for (int r = 0; r < 4; ++r){
                QH(wid, smp, g4 * 4 + r, l15) = f2bf(pr[r]);
                QH(wid, smp, g4 * 4 + r, 16 + l15) = 0;
            }
            // PV (K=32 zero-padded), attn-out into kh (dead after scores)
            bf16x8 pa = *(const bf16x8*)&QH(wid, smp, l15, g4 * 8);
            #pragma unroll
            for (int nb = 0; nb < 4; ++nb){
                bf16x8 vb = *(const bf16x8*)&VT(wid, smp, nb * 16 + l15, g4 * 8);
                f32x4 at = __builtin_amdgcn_mfma_f32_16x16x32_bf16(pa, vb, zero4, 0, 0, 0);
                #pragma unroll
                for (int r = 0; r < 4; ++r)
                    KH(wid, smp, g4 * 4 + r, nb * 16 + l15) = f2bf(at[r]);
            }
        }

        // ---- fused O-proj partial: acco += attn_h[32x64] @ Wo[:, hd*64:+64]^T ----
        // A-frags from wave-private KH (4 reads); B-frags from L2 (shared addresses).
        {
            bf16x8 af[4];
            #pragma unroll
            for (int kt = 0; kt < 4; ++kt)
                af[kt] = *(const bf16x8*)&KH(wid, l31 >> 4, l31 & 15, kt * 16 + h32 * 8);
            #pragma unroll
            for (int nb = 0; nb < 10; ++nb){
                #pragma unroll
                for (int kt = 0; kt < 4; ++kt){
                    bf16x8 b = *(const bf16x8*)(wof + ((size_t)(nb * 32 + hd * 4 + kt) * 64 + lane) * 8);
                    acco[nb] = __builtin_amdgcn_mfma_f32_32x32x16_bf16(af[kt], b, acco[nb], 0, 0, 0);
                }
            }
        }
    }
    #undef STAGE

    // ---- epilogue: proj[m][c] = acco + bias ----
    const size_t rbase = (size_t)m32 * 32;
    #pragma unroll
    for (int nb = 0; nb < 10; ++nb){
        float bn = bias[nb];
        #pragma unroll
        for (int r = 0; r < 16; ++r){
            int row = (r & 3) + 8 * (r >> 2) + 4 * h32;
            proj[(rbase + row) * CC + nb * 32 + l31] = f2bf(acco[nb][r] + bn);
        }
    }
}

// ---------------- kernel 4: residual + transpose back to (b,c,t,h,w) ----------------
__global__ __launch_bounds__(256) void k_res(const u16* __restrict__ proj, const float* __restrict__ x,
                                             float* __restrict__ out){
    __shared__ u16 tile[32][328];
    int wg = blockIdx.x;
    int t = wg & 15, h = (wg >> 4) & 31, b = wg >> 9;
    int tid = threadIdx.x;
    int s0 = (b * 32 + h) * 32;
    #pragma unroll
    for (int i = 0; i < 5; ++i){
        int ch = tid + 256 * i;
        int w = ch / 40, cc8 = (ch % 40) * 8;
        *(bf16x8*)(&tile[w][cc8]) = *(const bf16x8*)(proj + ((size_t)(s0 + w) * TT + t) * CC + cc8);
    }
    __syncthreads();
    int w = tid & 31, cq = tid >> 5;
    size_t base = ((size_t)(b * CC) * TT + t) * 1024 + h * 32 + w;
    for (int i = 0; i < 40; ++i){
        int c = cq * 40 + i;
        size_t idx = base + (size_t)c * 16384;
        out[idx] = x[idx] + bf2f(tile[w][c]);
    }
}

extern "C" void kernel_launch(void* const* d_in, const int* in_sizes, int n_in,
                              void* d_out, int out_size, void* d_ws, size_t ws_size,
                              hipStream_t stream){
    const float* hid = (const float*)d_in[0];
    const float* lnw = (const float*)d_in[1];
    const float* lnb = (const float*)d_in[2];
    const float* Wq  = (const float*)d_in[3];
    const float* Wk  = (const float*)d_in[4];
    const float* Wv  = (const float*)d_in[5];
    const float* Wo  = (const float*)d_in[6];
    const float* bo  = (const float*)d_in[7];

    char* ws = (char*)d_ws;
    u16* wqkv = (u16*)ws;                                   // 960 frags * 512 = 491,520 elems
    u16* wo_f = wqkv + (size_t)960 * 512;                   // 320 frags * 512 = 163,840 elems
    u16* xn   = wo_f + 163840;                              // 65536*320 (40 MB), 32-frag-major
    u16* proj = xn + (size_t)65536 * CC;                    // 65536*320 (40 MB), row-major

    k_wqkv32<<<240, 256, 0, stream>>>(Wq, Wk, Wv, wqkv);
    k_wo32  <<<80, 256, 0, stream>>>(Wo, wo_f);
    k_ln    <<<2048, 256, 0, stream>>>(hid, lnw, lnb, xn);
    k_attn  <<<512, 256, 0, stream>>>(xn, wqkv, wo_f, bo, proj);
    k_res   <<<2048, 256, 0, stream>>>(proj, hid, (float*)d_out);
}

// Round 12
// 229.151 us; speedup vs baseline: 1.7034x; 1.7034x over previous
//
#include <hip/hip_runtime.h>

#define TT 16
#define CC 320
#define NHEADS 8
#define DH 64
#define INNER 512

typedef float f32x4 __attribute__((ext_vector_type(4)));
typedef float f32x16 __attribute__((ext_vector_type(16)));
typedef short bf16x8 __attribute__((ext_vector_type(8)));
typedef unsigned short u16;

#define Z16 {0.f,0.f,0.f,0.f,0.f,0.f,0.f,0.f,0.f,0.f,0.f,0.f,0.f,0.f,0.f,0.f}

__device__ __forceinline__ float bf2f(u16 u){
    union { unsigned int i; float f; } v; v.i = ((unsigned int)u) << 16; return v.f;
}
__device__ __forceinline__ u16 f2bf(float f){
    union { float f; unsigned int i; } v; v.f = f;
    unsigned int x = v.i;
    return (u16)((x + 0x7fffu + ((x >> 16) & 1u)) >> 16);   // RNE
}

// ---------------- kernel 1a: Wq/Wk/Wv fp32 -> bf16 32x32x16-frag, 12KB-CHUNK-major ----------------
// frag f = ((hd*10 + c)*6 + nblk)*2 + kl ; kk = c*2 + kl (K-step 16)
// nblk 0,1=Q  2,3=K  4,5=V (32 cols each). Within frag: lane = ((k%16)>>3)*32 + (n%32), elem=k%8.
__global__ __launch_bounds__(256) void k_wqkv32(const float* __restrict__ wq, const float* __restrict__ wk,
                                                const float* __restrict__ wv, u16* __restrict__ dst){
    int gid  = blockIdx.x * 256 + threadIdx.x;   // 0..61439
    int lane = gid & 63;
    int f    = gid >> 6;                          // 0..959
    int local = f % 12;
    int kl   = local & 1;
    int nblk = local >> 1;
    int c    = (f / 12) % 10;
    int hd   = f / 120;
    int kk   = c * 2 + kl;
    const float* W = (nblk < 2) ? wq : (nblk < 4) ? wk : wv;
    int n  = hd * DH + (nblk & 1) * 32 + (lane & 31);
    int k0 = kk * 16 + (lane >> 5) * 8;
    const float* src = W + (size_t)n * CC + k0;
    f32x4 v0 = *(const f32x4*)src;
    f32x4 v1 = *(const f32x4*)(src + 4);
    bf16x8 o;
    o[0] = (short)f2bf(v0[0]); o[1] = (short)f2bf(v0[1]);
    o[2] = (short)f2bf(v0[2]); o[3] = (short)f2bf(v0[3]);
    o[4] = (short)f2bf(v1[0]); o[5] = (short)f2bf(v1[1]);
    o[6] = (short)f2bf(v1[2]); o[7] = (short)f2bf(v1[3]);
    *(bf16x8*)(dst + (size_t)gid * 8) = o;
}

// ---------------- kernel 1b: Wo fp32 -> bf16 16x16x32-frag-major ----------------
__global__ __launch_bounds__(256) void k_wo16(const float* __restrict__ wo, u16* __restrict__ dst){
    int idx  = blockIdx.x * 256 + threadIdx.x;   // 20480 frag-lanes
    int lane = idx & 63;
    int blk  = idx >> 6;
    int KT = INNER / 32;
    int n  = (blk / KT) * 16 + (lane & 15);
    int k0 = (blk % KT) * 32 + (lane >> 4) * 8;
    const float* src = wo + (size_t)n * INNER + k0;
    f32x4 v0 = *(const f32x4*)src;
    f32x4 v1 = *(const f32x4*)(src + 4);
    bf16x8 o;
    o[0] = (short)f2bf(v0[0]); o[1] = (short)f2bf(v0[1]);
    o[2] = (short)f2bf(v0[2]); o[3] = (short)f2bf(v0[3]);
    o[4] = (short)f2bf(v1[0]); o[5] = (short)f2bf(v1[1]);
    o[6] = (short)f2bf(v1[2]); o[7] = (short)f2bf(v1[3]);
    *(bf16x8*)(dst + (size_t)idx * 8) = o;
}

// ---------------- kernel 2: transpose + LayerNorm -> xn bf16 32x32x16 A-frag-major ----------------
// Pass 2 rewritten: each thread assembles one bf16x8 frag-chunk (unit = (w, c8)) and does a
// single 16B store; lnw/lnb staged in LDS. Output layout byte-identical to R8.
__global__ __launch_bounds__(256) void k_ln(const float* __restrict__ x, const float* __restrict__ lnw,
                                            const float* __restrict__ lnb, u16* __restrict__ xnf){
    __shared__ float tile[CC][37];
    __shared__ float psum[32][36];
    __shared__ float psq[32][36];
    __shared__ float meanb[32];
    __shared__ float rstdb[32];
    __shared__ float lnw_s[CC];
    __shared__ float lnb_s[CC];

    int wg = blockIdx.x;                 // (b,h,t)
    int t = wg & 15, h = (wg >> 4) & 31, b = wg >> 9;
    int tid = threadIdx.x;
    const size_t base = ((size_t)(b * CC) * TT + t) * 1024 + h * 32;

    // stage ln params
    if (tid < CC - 256){ lnw_s[256 + tid] = lnw[256 + tid]; lnb_s[256 + tid] = lnb[256 + tid]; }
    lnw_s[tid] = lnw[tid]; lnb_s[tid] = lnb[tid];

    int w4 = (tid & 7) * 4, cg = tid >> 3;
    f32x4 s4 = {0.f,0.f,0.f,0.f}, q4 = {0.f,0.f,0.f,0.f};
    for (int i = 0; i < 10; ++i){
        int c = cg * 10 + i;
        f32x4 v = *(const f32x4*)(x + base + (size_t)c * 16384 + w4);
        tile[c][w4 + 0] = v[0]; tile[c][w4 + 1] = v[1];
        tile[c][w4 + 2] = v[2]; tile[c][w4 + 3] = v[3];
        s4 += v; q4 += v * v;
    }
    psum[cg][w4 + 0] = s4[0]; psum[cg][w4 + 1] = s4[1]; psum[cg][w4 + 2] = s4[2]; psum[cg][w4 + 3] = s4[3];
    psq [cg][w4 + 0] = q4[0]; psq [cg][w4 + 1] = q4[1]; psq [cg][w4 + 2] = q4[2]; psq [cg][w4 + 3] = q4[3];
    __syncthreads();

    if (tid < 32){
        float s = 0.f, q = 0.f;
        for (int g = 0; g < 32; ++g){ s += psum[g][tid]; q += psq[g][tid]; }
        float mean = s * (1.f / CC);
        float var  = q * (1.f / CC) - mean * mean;
        meanb[tid] = mean;
        rstdb[tid] = rsqrtf(var + 1e-5f);
    }
    __syncthreads();

    // pass 2: 1280 units of (w, c8); each -> one 16B frag-chunk store
    int s_base = (b * 32 + h) * 32;
    #pragma unroll
    for (int j = 0; j < 5; ++j){
        int u = tid + 256 * j;              // 0..1279
        int w = u / 40, c8 = u % 40;
        float mean = meanb[w], rstd = rstdb[w];
        int s = s_base + w;
        int row = ((s & 1) << 4) | t;
        int kk = c8 >> 1;
        int lane_f = ((c8 & 1) << 5) | row;
        size_t m32 = (size_t)(s >> 1);
        bf16x8 o;
        #pragma unroll
        for (int e = 0; e < 8; ++e){
            int c = c8 * 8 + e;
            float nv = (tile[c][w] - mean) * rstd * lnw_s[c] + lnb_s[c];
            o[e] = (short)f2bf(nv);
        }
        *(bf16x8*)(xnf + ((size_t)(m32 * 20 + kk) * 64 + lane_f) * 8) = o;
    }
}

// ---------------- kernel 3: fused QKV + attention, LDS-staged weights (R8-exact) ----------------
#define QH(w,s,r,c) smem[((((w)*2+(s))*16+(r))*72) + (c)]
#define KH(w,s,r,c) smem[9216 + ((((w)*2+(s))*16+(r))*72) + (c)]
#define VT(w,s,d,k) smem[18432 + ((((w)*2+(s))*64+(d))*36) + (k)]

__global__ __launch_bounds__(256, 2) void k_attn(const u16* __restrict__ xnf,
                                                 const u16* __restrict__ wqkv,
                                                 u16* __restrict__ aof){
    // u16 indices: qh [0,9216) kh [9216,18432) vt [18432,36864)  (73,728 B total)
    // weight buffers overlay: buf0 = [0,6144), buf1 = [6144,12288)  (12KB each)
    __shared__ u16 smem[36864];

    const int tid  = threadIdx.x;
    const int lane = tid & 63;
    const int wid  = tid >> 6;        // 0..3
    const int l31  = lane & 31;
    const int h32  = lane >> 5;
    const int l15  = lane & 15;
    const int g4   = lane >> 4;
    const int m32  = blockIdx.x * 4 + wid;
    const f32x4 zero4 = {0.f, 0.f, 0.f, 0.f};

    // zero vt pad cols 16..31 once (vt region is never overlaid; per-head writes touch cols 0..15 only)
    #pragma unroll
    for (int j = 0; j < 32; ++j){
        int idx = j * 64 + lane;           // 0..2047 per wave slice
        int smp = idx >> 10;
        int d   = (idx >> 4) & 63;
        VT(wid, smp, d, 16 + (idx & 15)) = 0;
    }

    // persistent A-frags (this wave's 32 rows x 320 K), coalesced frag loads
    bf16x8 a_f[20];
    {
        const u16* xp = xnf + ((size_t)m32 * 20 * 64 + lane) * 8;
        #pragma unroll
        for (int kk = 0; kk < 20; ++kk)
            a_f[kk] = *(const bf16x8*)(xp + kk * 512);
    }

    #define STAGE(hd_, c_) do {                                                        \
        const u16* gsrc_ = wqkv + ((size_t)((hd_) * 10 + (c_)) * 6144);                \
        u16* ldst_ = (u16*)smem + ((c_) & 1) * 6144;                                   \
        _Pragma("unroll")                                                              \
        for (int i_ = 0; i_ < 3; ++i_)                                                 \
            __builtin_amdgcn_global_load_lds(                                          \
                (const __attribute__((address_space(1))) void*)(gsrc_ + (tid + i_ * 256) * 8), \
                (__attribute__((address_space(3))) void*)(ldst_ + (tid + i_ * 256) * 8),       \
                16, 0, 0);                                                             \
    } while (0)

    for (int hd = 0; hd < NHEADS; ++hd){
        // all waves done with prev head's qh/kh reads before staging clobbers them
        __builtin_amdgcn_sched_barrier(0);
        __builtin_amdgcn_s_barrier();
        __builtin_amdgcn_sched_barrier(0);

        STAGE(hd, 0);

        f32x16 acc[6];
        #pragma unroll
        for (int nb = 0; nb < 6; ++nb) acc[nb] = (f32x16)Z16;

        #pragma unroll
        for (int c = 0; c < 10; ++c){
            asm volatile("s_waitcnt vmcnt(0)" ::: "memory");
            __builtin_amdgcn_sched_barrier(0);
            __builtin_amdgcn_s_barrier();      // chunk c visible to all waves
            __builtin_amdgcn_sched_barrier(0);
            if (c < 9) STAGE(hd, c + 1);       // prefetch next chunk during compute
            const u16* wb = (const u16*)smem + (c & 1) * 6144;
            #pragma unroll
            for (int kl = 0; kl < 2; ++kl){
                #pragma unroll
                for (int nb = 0; nb < 6; ++nb){
                    bf16x8 b = *(const bf16x8*)(wb + (nb * 2 + kl) * 512 + lane * 8);
                    acc[nb] = __builtin_amdgcn_mfma_f32_32x32x16_bf16(a_f[c * 2 + kl], b, acc[nb], 0, 0, 0);
                }
            }
            __builtin_amdgcn_sched_barrier(0);
            __builtin_amdgcn_s_barrier();      // all waves done reading buf[c&1]
            __builtin_amdgcn_sched_barrier(0);
        }

        // ---- unpack QKV accumulators to wave-private LDS slices ----
        #pragma unroll
        for (int r = 0; r < 16; ++r){
            int row = (r & 3) + 8 * (r >> 2) + 4 * h32;   // verified 32x32 C layout
            int smp = row >> 4, tr = row & 15;
            QH(wid, smp, tr, l31)      = f2bf(acc[0][r] * 0.125f);   // pre-scale 1/sqrt(64)
            QH(wid, smp, tr, 32 + l31) = f2bf(acc[1][r] * 0.125f);
            KH(wid, smp, tr, l31)      = f2bf(acc[2][r]);
            KH(wid, smp, tr, 32 + l31) = f2bf(acc[3][r]);
            VT(wid, smp, l31, tr)      = f2bf(acc[4][r]);            // V^T: [d][key16]
            VT(wid, smp, 32 + l31, tr) = f2bf(acc[5][r]);
        }

        // ---- attention, per owned sample (wave-private) ----
        #pragma unroll
        for (int smp = 0; smp < 2; ++smp){
            f32x4 sc = zero4;
            #pragma unroll
            for (int k0 = 0; k0 < DH; k0 += 32){
                bf16x8 qa = *(const bf16x8*)&QH(wid, smp, l15, k0 + g4 * 8);
                bf16x8 kb = *(const bf16x8*)&KH(wid, smp, l15, k0 + g4 * 8);
                sc = __builtin_amdgcn_mfma_f32_16x16x32_bf16(qa, kb, sc, 0, 0, 0);
            }
            f32x4 pr;
            #pragma unroll
            for (int r = 0; r < 4; ++r){
                float m = sc[r];
                m = fmaxf(m, __shfl_xor(m, 1)); m = fmaxf(m, __shfl_xor(m, 2));
                m = fmaxf(m, __shfl_xor(m, 4)); m = fmaxf(m, __shfl_xor(m, 8));
                float e = __expf(sc[r] - m);
                float ss = e;
                ss += __shfl_xor(ss, 1); ss += __shfl_xor(ss, 2);
                ss += __shfl_xor(ss, 4); ss += __shfl_xor(ss, 8);
                pr[r] = e / ss;
            }
            // P -> qh cols 0..31 (Q dead); keys 16..31 zero
            #pragma unroll
            for (int r = 0; r < 4; ++r){
                QH(wid, smp, g4 * 4 + r, l15) = f2bf(pr[r]);
                QH(wid, smp, g4 * 4 + r, 16 + l15) = 0;
            }
            // PV (K=32 zero-padded), stage into kh (dead after scores)
            bf16x8 pa = *(const bf16x8*)&QH(wid, smp, l15, g4 * 8);
            #pragma unroll
            for (int nb = 0; nb < 4; ++nb){
                bf16x8 vb = *(const bf16x8*)&VT(wid, smp, nb * 16 + l15, g4 * 8);
                f32x4 at = __builtin_amdgcn_mfma_f32_16x16x32_bf16(pa, vb, zero4, 0, 0, 0);
                #pragma unroll
                for (int r = 0; r < 4; ++r)
                    KH(wid, smp, g4 * 4 + r, nb * 16 + l15) = f2bf(at[r]);
            }
            // coalesced frag-major store of attn-out (16x16x32-frag layout for k_oproj)
            const size_t sg = (size_t)m32 * 2 + smp;
            #pragma unroll
            for (int kkl = 0; kkl < 2; ++kkl){
                bf16x8 o8 = *(const bf16x8*)&KH(wid, smp, l15, kkl * 32 + g4 * 8);
                *(bf16x8*)(aof + ((sg * 16 + hd * 2 + kkl) * 64 + lane) * 8) = o8;
            }
        }
    }
    #undef STAGE
}

// ---------------- kernel 3b: O-proj GEMM  proj[65536][320] = ao[65536][512] @ Wo^T + bo ----------
__global__ __launch_bounds__(512, 4) void k_oproj(const u16* __restrict__ aof, const u16* __restrict__ wof,
                                                  const float* __restrict__ bo, u16* __restrict__ proj){
    const int tid  = threadIdx.x;
    const int lane = tid & 63;
    const int wid  = tid >> 6;
    const int l15  = lane & 15;
    const int g4   = lane >> 4;
    const int mh   = wid >> 1;
    const int nh   = wid & 1;
    const size_t mt0 = (size_t)blockIdx.x * 8 + mh * 2;
    const size_t m0  = mt0 * 16;

    f32x4 acc[10][2];
    #pragma unroll
    for (int j = 0; j < 10; ++j){
        acc[j][0] = (f32x4){0.f,0.f,0.f,0.f};
        acc[j][1] = (f32x4){0.f,0.f,0.f,0.f};
    }

    const u16* ap = aof + (mt0 * 16 * 64 + lane) * 8;
    const u16* wp = wof + (((size_t)nh * 10 * 16) * 64 + lane) * 8;

    #pragma unroll 2
    for (int kk = 0; kk < 16; ++kk){
        bf16x8 a0 = *(const bf16x8*)(ap + kk * 512);
        bf16x8 a1 = *(const bf16x8*)(ap + (16 + kk) * 512);
        #pragma unroll
        for (int j = 0; j < 10; ++j){
            bf16x8 b = *(const bf16x8*)(wp + (j * 16 + kk) * 512);
            acc[j][0] = __builtin_amdgcn_mfma_f32_16x16x32_bf16(a0, b, acc[j][0], 0, 0, 0);
            acc[j][1] = __builtin_amdgcn_mfma_f32_16x16x32_bf16(a1, b, acc[j][1], 0, 0, 0);
        }
    }

    #pragma unroll
    for (int j = 0; j < 10; ++j){
        int c = nh * 160 + j * 16 + l15;
        float bias = bo[c];
        #pragma unroll
        for (int mb = 0; mb < 2; ++mb){
            size_t row0 = m0 + mb * 16 + g4 * 4;
            #pragma unroll
            for (int r = 0; r < 4; ++r)
                proj[(row0 + r) * CC + c] = f2bf(acc[j][mb][r] + bias);
        }
    }
}

// ---------------- kernel 4: residual + transpose back to (b,c,t,h,w), float4 along w ----------------
__global__ __launch_bounds__(256) void k_res(const u16* __restrict__ proj, const float* __restrict__ x,
                                             float* __restrict__ out){
    __shared__ u16 tile[32][328];   // [w][c]
    int wg = blockIdx.x;
    int t = wg & 15, h = (wg >> 4) & 31, b = wg >> 9;
    int tid = threadIdx.x;
    int s0 = (b * 32 + h) * 32;
    #pragma unroll
    for (int i = 0; i < 5; ++i){
        int ch = tid + 256 * i;
        int w = ch / 40, cc8 = (ch % 40) * 8;
        *(bf16x8*)(&tile[w][cc8]) = *(const bf16x8*)(proj + ((size_t)(s0 + w) * TT + t) * CC + cc8);
    }
    __syncthreads();
    // vectorized: thread = (w-quad, c-group); float4 read/modify/write along w
    int w4 = (tid & 7) * 4;
    int cg = tid >> 3;               // 0..31
    size_t base = ((size_t)(b * CC) * TT + t) * 1024 + h * 32 + w4;
    #pragma unroll
    for (int i = 0; i < 10; ++i){
        int c = cg * 10 + i;
        size_t idx = base + (size_t)c * 16384;
        f32x4 xv = *(const f32x4*)(x + idx);
        f32x4 o;
        o[0] = xv[0] + bf2f(tile[w4 + 0][c]);
        o[1] = xv[1] + bf2f(tile[w4 + 1][c]);
        o[2] = xv[2] + bf2f(tile[w4 + 2][c]);
        o[3] = xv[3] + bf2f(tile[w4 + 3][c]);
        *(f32x4*)(out + idx) = o;
    }
}

extern "C" void kernel_launch(void* const* d_in, const int* in_sizes, int n_in,
                              void* d_out, int out_size, void* d_ws, size_t ws_size,
                              hipStream_t stream){
    const float* hid = (const float*)d_in[0];
    const float* lnw = (const float*)d_in[1];
    const float* lnb = (const float*)d_in[2];
    const float* Wq  = (const float*)d_in[3];
    const float* Wk  = (const float*)d_in[4];
    const float* Wv  = (const float*)d_in[5];
    const float* Wo  = (const float*)d_in[6];
    const float* bo  = (const float*)d_in[7];

    char* ws = (char*)d_ws;
    u16* wqkv = (u16*)ws;                                   // 960 frags * 512 = 491,520 elems
    u16* wo_f = wqkv + (size_t)960 * 512;                   // 163,840 elems
    u16* ao   = wo_f + 163840;                              // 65536*512 (67 MB), 16-frag-major
    u16* xn   = ao + (size_t)65536 * INNER;                 // 65536*320 (40 MB), 32-frag-major
    u16* proj = xn;                                         // reuse: xn dead after k_attn

    k_wqkv32<<<240, 256, 0, stream>>>(Wq, Wk, Wv, wqkv);
    k_wo16  <<<80, 256, 0, stream>>>(Wo, wo_f);
    k_ln    <<<2048, 256, 0, stream>>>(hid, lnw, lnb, xn);
    k_attn  <<<512, 256, 0, stream>>>(xn, wqkv, ao);
    k_oproj <<<512, 512, 0, stream>>>(ao, wo_f, bo, proj);
    k_res   <<<2048, 256, 0, stream>>>(proj, hid, (float*)d_out);
}

// Round 13
// 216.969 us; speedup vs baseline: 1.7990x; 1.0561x over previous
//
#include <hip/hip_runtime.h>

#define TT 16
#define CC 320
#define NHEADS 8
#define DH 64
#define INNER 512

typedef float f32x4 __attribute__((ext_vector_type(4)));
typedef float f32x16 __attribute__((ext_vector_type(16)));
typedef short bf16x8 __attribute__((ext_vector_type(8)));
typedef unsigned short u16;

#define Z16 {0.f,0.f,0.f,0.f,0.f,0.f,0.f,0.f,0.f,0.f,0.f,0.f,0.f,0.f,0.f,0.f}

__device__ __forceinline__ float bf2f(u16 u){
    union { unsigned int i; float f; } v; v.i = ((unsigned int)u) << 16; return v.f;
}
__device__ __forceinline__ u16 f2bf(float f){
    union { float f; unsigned int i; } v; v.f = f;
    unsigned int x = v.i;
    return (u16)((x + 0x7fffu + ((x >> 16) & 1u)) >> 16);   // RNE
}

// ---------------- kernel 1a: Wq/Wk/Wv fp32 -> bf16 32x32x16-frag, 12KB-CHUNK-major ----------------
// frag f = ((hd*10 + c)*6 + nblk)*2 + kl ; kk = c*2 + kl (K-step 16)
// nblk 0,1=Q  2,3=K  4,5=V (32 cols each). Within frag: lane = ((k%16)>>3)*32 + (n%32), elem=k%8.
__global__ __launch_bounds__(256) void k_wqkv32(const float* __restrict__ wq, const float* __restrict__ wk,
                                                const float* __restrict__ wv, u16* __restrict__ dst){
    int gid  = blockIdx.x * 256 + threadIdx.x;   // 0..61439
    int lane = gid & 63;
    int f    = gid >> 6;                          // 0..959
    int local = f % 12;
    int kl   = local & 1;
    int nblk = local >> 1;
    int c    = (f / 12) % 10;
    int hd   = f / 120;
    int kk   = c * 2 + kl;
    const float* W = (nblk < 2) ? wq : (nblk < 4) ? wk : wv;
    int n  = hd * DH + (nblk & 1) * 32 + (lane & 31);
    int k0 = kk * 16 + (lane >> 5) * 8;
    const float* src = W + (size_t)n * CC + k0;
    f32x4 v0 = *(const f32x4*)src;
    f32x4 v1 = *(const f32x4*)(src + 4);
    bf16x8 o;
    o[0] = (short)f2bf(v0[0]); o[1] = (short)f2bf(v0[1]);
    o[2] = (short)f2bf(v0[2]); o[3] = (short)f2bf(v0[3]);
    o[4] = (short)f2bf(v1[0]); o[5] = (short)f2bf(v1[1]);
    o[6] = (short)f2bf(v1[2]); o[7] = (short)f2bf(v1[3]);
    *(bf16x8*)(dst + (size_t)gid * 8) = o;
}

// ---------------- kernel 1b: Wo fp32 -> bf16 32x32x16-frag-major (R11-verified) ----------------
// frag f = nb*32 + kt (nb 0..9 n-blocks of 32, kt 0..31 k-tiles of 16).
// Within frag: lane = ((k%16)>>3)*32 + (n%32), elem = k%8.
__global__ __launch_bounds__(256) void k_wo32(const float* __restrict__ wo, u16* __restrict__ dst){
    int gid  = blockIdx.x * 256 + threadIdx.x;   // 0..20479
    int lane = gid & 63;
    int f    = gid >> 6;                          // 0..319
    int kt   = f & 31;
    int nb   = f >> 5;
    int n  = nb * 32 + (lane & 31);
    int k0 = kt * 16 + (lane >> 5) * 8;
    const float* src = wo + (size_t)n * INNER + k0;
    f32x4 v0 = *(const f32x4*)src;
    f32x4 v1 = *(const f32x4*)(src + 4);
    bf16x8 o;
    o[0] = (short)f2bf(v0[0]); o[1] = (short)f2bf(v0[1]);
    o[2] = (short)f2bf(v0[2]); o[3] = (short)f2bf(v0[3]);
    o[4] = (short)f2bf(v1[0]); o[5] = (short)f2bf(v1[1]);
    o[6] = (short)f2bf(v1[2]); o[7] = (short)f2bf(v1[3]);
    *(bf16x8*)(dst + (size_t)gid * 8) = o;
}

// ---------------- kernel 2: transpose + LayerNorm -> xn bf16 32x32x16 A-frag-major ----------------
__global__ __launch_bounds__(256) void k_ln(const float* __restrict__ x, const float* __restrict__ lnw,
                                            const float* __restrict__ lnb, u16* __restrict__ xnf){
    __shared__ float tile[CC][37];
    __shared__ float psum[32][36];
    __shared__ float psq[32][36];
    __shared__ float meanb[32];
    __shared__ float rstdb[32];
    __shared__ float lnw_s[CC];
    __shared__ float lnb_s[CC];

    int wg = blockIdx.x;                 // (b,h,t)
    int t = wg & 15, h = (wg >> 4) & 31, b = wg >> 9;
    int tid = threadIdx.x;
    const size_t base = ((size_t)(b * CC) * TT + t) * 1024 + h * 32;

    if (tid < CC - 256){ lnw_s[256 + tid] = lnw[256 + tid]; lnb_s[256 + tid] = lnb[256 + tid]; }
    lnw_s[tid] = lnw[tid]; lnb_s[tid] = lnb[tid];

    int w4 = (tid & 7) * 4, cg = tid >> 3;
    f32x4 s4 = {0.f,0.f,0.f,0.f}, q4 = {0.f,0.f,0.f,0.f};
    for (int i = 0; i < 10; ++i){
        int c = cg * 10 + i;
        f32x4 v = *(const f32x4*)(x + base + (size_t)c * 16384 + w4);
        tile[c][w4 + 0] = v[0]; tile[c][w4 + 1] = v[1];
        tile[c][w4 + 2] = v[2]; tile[c][w4 + 3] = v[3];
        s4 += v; q4 += v * v;
    }
    psum[cg][w4 + 0] = s4[0]; psum[cg][w4 + 1] = s4[1]; psum[cg][w4 + 2] = s4[2]; psum[cg][w4 + 3] = s4[3];
    psq [cg][w4 + 0] = q4[0]; psq [cg][w4 + 1] = q4[1]; psq [cg][w4 + 2] = q4[2]; psq [cg][w4 + 3] = q4[3];
    __syncthreads();

    if (tid < 32){
        float s = 0.f, q = 0.f;
        for (int g = 0; g < 32; ++g){ s += psum[g][tid]; q += psq[g][tid]; }
        float mean = s * (1.f / CC);
        float var  = q * (1.f / CC) - mean * mean;
        meanb[tid] = mean;
        rstdb[tid] = rsqrtf(var + 1e-5f);
    }
    __syncthreads();

    int s_base = (b * 32 + h) * 32;
    #pragma unroll
    for (int j = 0; j < 5; ++j){
        int u = tid + 256 * j;              // 0..1279
        int w = u / 40, c8 = u % 40;
        float mean = meanb[w], rstd = rstdb[w];
        int s = s_base + w;
        int row = ((s & 1) << 4) | t;
        int kk = c8 >> 1;
        int lane_f = ((c8 & 1) << 5) | row;
        size_t m32 = (size_t)(s >> 1);
        bf16x8 o;
        #pragma unroll
        for (int e = 0; e < 8; ++e){
            int c = c8 * 8 + e;
            float nv = (tile[c][w] - mean) * rstd * lnw_s[c] + lnb_s[c];
            o[e] = (short)f2bf(nv);
        }
        *(bf16x8*)(xnf + ((size_t)(m32 * 20 + kk) * 64 + lane_f) * 8) = o;
    }
}

// ---------------- kernel 3: fused QKV + attention, LDS-staged weights (R8-exact schedule) ----------------
// ONLY change vs R8/R12: attn-out store layout -> aot[t][sample][k] (for k_oproj_res).
#define QH(w,s,r,c) smem[((((w)*2+(s))*16+(r))*72) + (c)]
#define KH(w,s,r,c) smem[9216 + ((((w)*2+(s))*16+(r))*72) + (c)]
#define VT(w,s,d,k) smem[18432 + ((((w)*2+(s))*64+(d))*36) + (k)]

__global__ __launch_bounds__(256, 2) void k_attn(const u16* __restrict__ xnf,
                                                 const u16* __restrict__ wqkv,
                                                 u16* __restrict__ aot){
    // u16 indices: qh [0,9216) kh [9216,18432) vt [18432,36864)  (73,728 B total)
    // weight buffers overlay: buf0 = [0,6144), buf1 = [6144,12288)  (12KB each)
    __shared__ u16 smem[36864];

    const int tid  = threadIdx.x;
    const int lane = tid & 63;
    const int wid  = tid >> 6;        // 0..3
    const int l31  = lane & 31;
    const int h32  = lane >> 5;
    const int l15  = lane & 15;
    const int g4   = lane >> 4;
    const int m32  = blockIdx.x * 4 + wid;
    const f32x4 zero4 = {0.f, 0.f, 0.f, 0.f};

    // zero vt pad cols 16..31 once
    #pragma unroll
    for (int j = 0; j < 32; ++j){
        int idx = j * 64 + lane;
        int smp = idx >> 10;
        int d   = (idx >> 4) & 63;
        VT(wid, smp, d, 16 + (idx & 15)) = 0;
    }

    // persistent A-frags (this wave's 32 rows x 320 K), coalesced frag loads
    bf16x8 a_f[20];
    {
        const u16* xp = xnf + ((size_t)m32 * 20 * 64 + lane) * 8;
        #pragma unroll
        for (int kk = 0; kk < 20; ++kk)
            a_f[kk] = *(const bf16x8*)(xp + kk * 512);
    }

    #define STAGE(hd_, c_) do {                                                        \
        const u16* gsrc_ = wqkv + ((size_t)((hd_) * 10 + (c_)) * 6144);                \
        u16* ldst_ = (u16*)smem + ((c_) & 1) * 6144;                                   \
        _Pragma("unroll")                                                              \
        for (int i_ = 0; i_ < 3; ++i_)                                                 \
            __builtin_amdgcn_global_load_lds(                                          \
                (const __attribute__((address_space(1))) void*)(gsrc_ + (tid + i_ * 256) * 8), \
                (__attribute__((address_space(3))) void*)(ldst_ + (tid + i_ * 256) * 8),       \
                16, 0, 0);                                                             \
    } while (0)

    for (int hd = 0; hd < NHEADS; ++hd){
        __builtin_amdgcn_sched_barrier(0);
        __builtin_amdgcn_s_barrier();
        __builtin_amdgcn_sched_barrier(0);

        STAGE(hd, 0);

        f32x16 acc[6];
        #pragma unroll
        for (int nb = 0; nb < 6; ++nb) acc[nb] = (f32x16)Z16;

        #pragma unroll
        for (int c = 0; c < 10; ++c){
            asm volatile("s_waitcnt vmcnt(0)" ::: "memory");
            __builtin_amdgcn_sched_barrier(0);
            __builtin_amdgcn_s_barrier();      // chunk c visible to all waves
            __builtin_amdgcn_sched_barrier(0);
            if (c < 9) STAGE(hd, c + 1);       // prefetch next chunk during compute
            const u16* wb = (const u16*)smem + (c & 1) * 6144;
            #pragma unroll
            for (int kl = 0; kl < 2; ++kl){
                #pragma unroll
                for (int nb = 0; nb < 6; ++nb){
                    bf16x8 b = *(const bf16x8*)(wb + (nb * 2 + kl) * 512 + lane * 8);
                    acc[nb] = __builtin_amdgcn_mfma_f32_32x32x16_bf16(a_f[c * 2 + kl], b, acc[nb], 0, 0, 0);
                }
            }
            __builtin_amdgcn_sched_barrier(0);
            __builtin_amdgcn_s_barrier();      // all waves done reading buf[c&1]
            __builtin_amdgcn_sched_barrier(0);
        }

        // ---- unpack QKV accumulators to wave-private LDS slices ----
        #pragma unroll
        for (int r = 0; r < 16; ++r){
            int row = (r & 3) + 8 * (r >> 2) + 4 * h32;   // verified 32x32 C layout
            int smp = row >> 4, tr = row & 15;
            QH(wid, smp, tr, l31)      = f2bf(acc[0][r] * 0.125f);   // pre-scale 1/sqrt(64)
            QH(wid, smp, tr, 32 + l31) = f2bf(acc[1][r] * 0.125f);
            KH(wid, smp, tr, l31)      = f2bf(acc[2][r]);
            KH(wid, smp, tr, 32 + l31) = f2bf(acc[3][r]);
            VT(wid, smp, l31, tr)      = f2bf(acc[4][r]);            // V^T: [d][key16]
            VT(wid, smp, 32 + l31, tr) = f2bf(acc[5][r]);
        }

        // ---- attention, per owned sample (wave-private) ----
        #pragma unroll
        for (int smp = 0; smp < 2; ++smp){
            f32x4 sc = zero4;
            #pragma unroll
            for (int k0 = 0; k0 < DH; k0 += 32){
                bf16x8 qa = *(const bf16x8*)&QH(wid, smp, l15, k0 + g4 * 8);
                bf16x8 kb = *(const bf16x8*)&KH(wid, smp, l15, k0 + g4 * 8);
                sc = __builtin_amdgcn_mfma_f32_16x16x32_bf16(qa, kb, sc, 0, 0, 0);
            }
            f32x4 pr;
            #pragma unroll
            for (int r = 0; r < 4; ++r){
                float m = sc[r];
                m = fmaxf(m, __shfl_xor(m, 1)); m = fmaxf(m, __shfl_xor(m, 2));
                m = fmaxf(m, __shfl_xor(m, 4)); m = fmaxf(m, __shfl_xor(m, 8));
                float e = __expf(sc[r] - m);
                float ss = e;
                ss += __shfl_xor(ss, 1); ss += __shfl_xor(ss, 2);
                ss += __shfl_xor(ss, 4); ss += __shfl_xor(ss, 8);
                pr[r] = e / ss;
            }
            // P -> qh cols 0..31 (Q dead); keys 16..31 zero
            #pragma unroll
            for (int r = 0; r < 4; ++r){
                QH(wid, smp, g4 * 4 + r, l15) = f2bf(pr[r]);
                QH(wid, smp, g4 * 4 + r, 16 + l15) = 0;
            }
            // PV (K=32 zero-padded), stage into kh (dead after scores)
            bf16x8 pa = *(const bf16x8*)&QH(wid, smp, l15, g4 * 8);
            #pragma unroll
            for (int nb = 0; nb < 4; ++nb){
                bf16x8 vb = *(const bf16x8*)&VT(wid, smp, nb * 16 + l15, g4 * 8);
                f32x4 at = __builtin_amdgcn_mfma_f32_16x16x32_bf16(pa, vb, zero4, 0, 0, 0);
                #pragma unroll
                for (int r = 0; r < 4; ++r)
                    KH(wid, smp, g4 * 4 + r, nb * 16 + l15) = f2bf(at[r]);
            }
            // store attn-out to aot[t][sample][k]: 16 x 64B segments per store op
            const size_t sg = (size_t)m32 * 2 + smp;
            #pragma unroll
            for (int kkl = 0; kkl < 2; ++kkl){
                bf16x8 o8 = *(const bf16x8*)&KH(wid, smp, l15, kkl * 32 + g4 * 8);
                *(bf16x8*)(aot + ((size_t)l15 * 4096 + sg) * 512 + hd * 64 + kkl * 32 + g4 * 8) = o8;
            }
        }
    }
    #undef STAGE
}

// ---------------- kernel 3b: fused O-proj + bias + residual + transpose-out ----------------
// WG = (b,h,t): 32 samples (w=0..31) x 320 cols, K=512. A rows contiguous in aot.
// 4 waves split 10 c-blocks (3/3/2/2). A staged in padded LDS (stride 516 -> 2-way-free
// b128 reads); B = Wo 32x32-frags from L2 (same addresses across all WGs).
__global__ __launch_bounds__(256) void k_oproj_res(const u16* __restrict__ aot, const u16* __restrict__ wof,
                                                   const float* __restrict__ bo, const float* __restrict__ x,
                                                   float* __restrict__ out){
    __shared__ u16 atile[32 * 516];       // [sample][k], row stride 516 (2-way-free)
    __shared__ float otile[4][32 * 36];   // per-wave [c][w], row stride 36

    const int tid  = threadIdx.x;
    const int lane = tid & 63;
    const int wid  = tid >> 6;            // 0..3
    const int l31  = lane & 31;
    const int h32  = lane >> 5;
    int wg = blockIdx.x;                  // (b,h,t)
    int t = wg & 15, h = (wg >> 4) & 31, b = wg >> 9;
    const int s0 = (b * 32 + h) * 32;

    // stage A: 32 rows x 512 (32KB contiguous in aot) -> padded LDS (reg-staged)
    {
        const u16* src = aot + ((size_t)t * 4096 + s0) * 512;
        #pragma unroll
        for (int i = 0; i < 8; ++i){
            int flat = tid + 256 * i;          // 0..2047
            int row = flat >> 6, c16 = flat & 63;
            bf16x8 v = *(const bf16x8*)(src + (size_t)flat * 8);
            *(bf16x8*)(atile + row * 516 + c16 * 8) = v;
        }
    }
    __syncthreads();

    // wave's c-block range: 3/3/2/2
    const int nb_start = (wid < 2) ? wid * 3 : 6 + (wid - 2) * 2;
    const int nb_count = (wid < 2) ? 3 : 2;

    for (int j = 0; j < nb_count; ++j){
        const int nb = nb_start + j;
        f32x16 acc = (f32x16)Z16;
        const u16* wp = wof + ((size_t)(nb * 32) * 64 + lane) * 8;
        #pragma unroll
        for (int kt = 0; kt < 32; ++kt){
            bf16x8 af = *(const bf16x8*)(atile + l31 * 516 + kt * 16 + h32 * 8);
            bf16x8 bf = *(const bf16x8*)(wp + (size_t)kt * 512);
            acc = __builtin_amdgcn_mfma_f32_32x32x16_bf16(af, bf, acc, 0, 0, 0);
        }
        // C layout: col = l31 (c within block), row = (r&3)+8*(r>>2)+4*h32 (= w)
        float bias_v = bo[nb * 32 + l31];
        #pragma unroll
        for (int r = 0; r < 16; ++r){
            int row = (r & 3) + 8 * (r >> 2) + 4 * h32;
            otile[wid][l31 * 36 + row] = acc[r] + bias_v;
        }
        // residual + coalesced float4 write along w (same wave; compiler orders LDS RAW)
        int cl = lane >> 3;                   // 0..7
        int w4 = (lane & 7) * 4;
        #pragma unroll
        for (int ci = 0; ci < 4; ++ci){
            int c = ci * 8 + cl;
            size_t idx = ((size_t)(b * CC + nb * 32 + c) * TT + t) * 1024 + h * 32 + w4;
            f32x4 ov = *(const f32x4*)(&otile[wid][c * 36 + w4]);
            f32x4 xv = *(const f32x4*)(x + idx);
            *(f32x4*)(out + idx) = xv + ov;
        }
    }
}

extern "C" void kernel_launch(void* const* d_in, const int* in_sizes, int n_in,
                              void* d_out, int out_size, void* d_ws, size_t ws_size,
                              hipStream_t stream){
    const float* hid = (const float*)d_in[0];
    const float* lnw = (const float*)d_in[1];
    const float* lnb = (const float*)d_in[2];
    const float* Wq  = (const float*)d_in[3];
    const float* Wk  = (const float*)d_in[4];
    const float* Wv  = (const float*)d_in[5];
    const float* Wo  = (const float*)d_in[6];
    const float* bo  = (const float*)d_in[7];

    char* ws = (char*)d_ws;
    u16* wqkv = (u16*)ws;                                   // 960 frags * 512 = 491,520 elems
    u16* wo_f = wqkv + (size_t)960 * 512;                   // 320 frags * 512 = 163,840 elems
    u16* aot  = wo_f + 163840;                              // 16*4096*512 (67 MB), [t][sample][k]
    u16* xn   = aot + (size_t)TT * 4096 * INNER;            // 65536*320 (40 MB), 32-frag-major

    k_wqkv32   <<<240, 256, 0, stream>>>(Wq, Wk, Wv, wqkv);
    k_wo32     <<<80, 256, 0, stream>>>(Wo, wo_f);
    k_ln       <<<2048, 256, 0, stream>>>(hid, lnw, lnb, xn);
    k_attn     <<<512, 256, 0, stream>>>(xn, wqkv, aot);
    k_oproj_res<<<2048, 256, 0, stream>>>(aot, wo_f, bo, hid, (float*)d_out);
}

// Round 14
// 210.298 us; speedup vs baseline: 1.8561x; 1.0317x over previous
//
#include <hip/hip_runtime.h>

#define TT 16
#define CC 320
#define NHEADS 8
#define DH 64
#define INNER 512

typedef float f32x4 __attribute__((ext_vector_type(4)));
typedef float f32x16 __attribute__((ext_vector_type(16)));
typedef short bf16x8 __attribute__((ext_vector_type(8)));
typedef unsigned short u16;

#define Z16 {0.f,0.f,0.f,0.f,0.f,0.f,0.f,0.f,0.f,0.f,0.f,0.f,0.f,0.f,0.f,0.f}

__device__ __forceinline__ float bf2f(u16 u){
    union { unsigned int i; float f; } v; v.i = ((unsigned int)u) << 16; return v.f;
}
__device__ __forceinline__ u16 f2bf(float f){
    union { float f; unsigned int i; } v; v.f = f;
    unsigned int x = v.i;
    return (u16)((x + 0x7fffu + ((x >> 16) & 1u)) >> 16);   // RNE
}

// ---------------- kernel 1: merged weight prep ----------------
// blk < 240: Wq/Wk/Wv -> bf16 32x32x16-frag, 12KB-CHUNK-major
//   frag f = ((hd*10 + c)*6 + nblk)*2 + kl ; kk = c*2 + kl (K-step 16)
//   nblk 0,1=Q 2,3=K 4,5=V. lane = ((k%16)>>3)*32 + (n%32), elem=k%8.
// blk >= 240: Wo -> bf16 32x32x16-frag-major: frag f = nb*32 + kt.
__global__ __launch_bounds__(256) void k_wprep(const float* __restrict__ wq, const float* __restrict__ wk,
                                               const float* __restrict__ wv, const float* __restrict__ wo,
                                               u16* __restrict__ dqkv, u16* __restrict__ dwo){
    int blk = blockIdx.x;
    if (blk < 240){
        int gid  = blk * 256 + threadIdx.x;          // 0..61439
        int lane = gid & 63;
        int f    = gid >> 6;                          // 0..959
        int local = f % 12;
        int kl   = local & 1;
        int nblk = local >> 1;
        int c    = (f / 12) % 10;
        int hd   = f / 120;
        int kk   = c * 2 + kl;
        const float* W = (nblk < 2) ? wq : (nblk < 4) ? wk : wv;
        int n  = hd * DH + (nblk & 1) * 32 + (lane & 31);
        int k0 = kk * 16 + (lane >> 5) * 8;
        const float* src = W + (size_t)n * CC + k0;
        f32x4 v0 = *(const f32x4*)src;
        f32x4 v1 = *(const f32x4*)(src + 4);
        bf16x8 o;
        o[0] = (short)f2bf(v0[0]); o[1] = (short)f2bf(v0[1]);
        o[2] = (short)f2bf(v0[2]); o[3] = (short)f2bf(v0[3]);
        o[4] = (short)f2bf(v1[0]); o[5] = (short)f2bf(v1[1]);
        o[6] = (short)f2bf(v1[2]); o[7] = (short)f2bf(v1[3]);
        *(bf16x8*)(dqkv + (size_t)gid * 8) = o;
    } else {
        int gid  = (blk - 240) * 256 + threadIdx.x;  // 0..20479
        int lane = gid & 63;
        int f    = gid >> 6;                          // 0..319
        int kt   = f & 31;
        int nb   = f >> 5;
        int n  = nb * 32 + (lane & 31);
        int k0 = kt * 16 + (lane >> 5) * 8;
        const float* src = wo + (size_t)n * INNER + k0;
        f32x4 v0 = *(const f32x4*)src;
        f32x4 v1 = *(const f32x4*)(src + 4);
        bf16x8 o;
        o[0] = (short)f2bf(v0[0]); o[1] = (short)f2bf(v0[1]);
        o[2] = (short)f2bf(v0[2]); o[3] = (short)f2bf(v0[3]);
        o[4] = (short)f2bf(v1[0]); o[5] = (short)f2bf(v1[1]);
        o[6] = (short)f2bf(v1[2]); o[7] = (short)f2bf(v1[3]);
        *(bf16x8*)(dwo + (size_t)gid * 8) = o;
    }
}

// ---------------- kernel 2: transpose + LayerNorm -> xn bf16 32x32x16 A-frag-major ----------------
__global__ __launch_bounds__(256) void k_ln(const float* __restrict__ x, const float* __restrict__ lnw,
                                            const float* __restrict__ lnb, u16* __restrict__ xnf){
    __shared__ float tile[CC][37];
    __shared__ float psum[32][36];
    __shared__ float psq[32][36];
    __shared__ float meanb[32];
    __shared__ float rstdb[32];
    __shared__ float lnw_s[CC];
    __shared__ float lnb_s[CC];

    int wg = blockIdx.x;                 // (b,h,t)
    int t = wg & 15, h = (wg >> 4) & 31, b = wg >> 9;
    int tid = threadIdx.x;
    const size_t base = ((size_t)(b * CC) * TT + t) * 1024 + h * 32;

    if (tid < CC - 256){ lnw_s[256 + tid] = lnw[256 + tid]; lnb_s[256 + tid] = lnb[256 + tid]; }
    lnw_s[tid] = lnw[tid]; lnb_s[tid] = lnb[tid];

    int w4 = (tid & 7) * 4, cg = tid >> 3;
    f32x4 s4 = {0.f,0.f,0.f,0.f}, q4 = {0.f,0.f,0.f,0.f};
    for (int i = 0; i < 10; ++i){
        int c = cg * 10 + i;
        f32x4 v = *(const f32x4*)(x + base + (size_t)c * 16384 + w4);
        tile[c][w4 + 0] = v[0]; tile[c][w4 + 1] = v[1];
        tile[c][w4 + 2] = v[2]; tile[c][w4 + 3] = v[3];
        s4 += v; q4 += v * v;
    }
    psum[cg][w4 + 0] = s4[0]; psum[cg][w4 + 1] = s4[1]; psum[cg][w4 + 2] = s4[2]; psum[cg][w4 + 3] = s4[3];
    psq [cg][w4 + 0] = q4[0]; psq [cg][w4 + 1] = q4[1]; psq [cg][w4 + 2] = q4[2]; psq [cg][w4 + 3] = q4[3];
    __syncthreads();

    if (tid < 32){
        float s = 0.f, q = 0.f;
        for (int g = 0; g < 32; ++g){ s += psum[g][tid]; q += psq[g][tid]; }
        float mean = s * (1.f / CC);
        float var  = q * (1.f / CC) - mean * mean;
        meanb[tid] = mean;
        rstdb[tid] = rsqrtf(var + 1e-5f);
    }
    __syncthreads();

    int s_base = (b * 32 + h) * 32;
    #pragma unroll
    for (int j = 0; j < 5; ++j){
        int u = tid + 256 * j;              // 0..1279
        int w = u / 40, c8 = u % 40;
        float mean = meanb[w], rstd = rstdb[w];
        int s = s_base + w;
        int row = ((s & 1) << 4) | t;
        int kk = c8 >> 1;
        int lane_f = ((c8 & 1) << 5) | row;
        size_t m32 = (size_t)(s >> 1);
        bf16x8 o;
        #pragma unroll
        for (int e = 0; e < 8; ++e){
            int c = c8 * 8 + e;
            float nv = (tile[c][w] - mean) * rstd * lnw_s[c] + lnb_s[c];
            o[e] = (short)f2bf(nv);
        }
        *(bf16x8*)(xnf + ((size_t)(m32 * 20 + kk) * 64 + lane_f) * 8) = o;
    }
}

// ---------------- kernel 3: fused QKV + attention, LDS-staged weights ----------------
// R13 math byte-identical. Schedule: TRIPLE-buffer rotation (3 x 12KB = exactly qh+kh)
// with prefetch-1 -> the per-chunk post-compute barrier is redundant (the buffer being
// staged was last read 2 chunks ago, already separated by >=1 barrier). 12 barriers/head
// (vs 21). vt region (with persistent zero pads) never overlaid.
#define QH(w,s,r,c) smem[((((w)*2+(s))*16+(r))*72) + (c)]
#define KH(w,s,r,c) smem[9216 + ((((w)*2+(s))*16+(r))*72) + (c)]
#define VT(w,s,d,k) smem[18432 + ((((w)*2+(s))*64+(d))*36) + (k)]

__global__ __launch_bounds__(256, 2) void k_attn(const u16* __restrict__ xnf,
                                                 const u16* __restrict__ wqkv,
                                                 u16* __restrict__ aot){
    // u16 indices: qh [0,9216) kh [9216,18432) vt [18432,36864)  (73,728 B total)
    // weight buffers overlay qh+kh: buf_i = [i*6144, (i+1)*6144), i=0..2
    __shared__ u16 smem[36864];

    const int tid  = threadIdx.x;
    const int lane = tid & 63;
    const int wid  = tid >> 6;        // 0..3
    const int l31  = lane & 31;
    const int h32  = lane >> 5;
    const int l15  = lane & 15;
    const int g4   = lane >> 4;
    const int m32  = blockIdx.x * 4 + wid;
    const f32x4 zero4 = {0.f, 0.f, 0.f, 0.f};

    // zero vt pad cols 16..31 once (vt never overlaid; per-head writes touch cols 0..15 only)
    #pragma unroll
    for (int j = 0; j < 32; ++j){
        int idx = j * 64 + lane;
        int smp = idx >> 10;
        int d   = (idx >> 4) & 63;
        VT(wid, smp, d, 16 + (idx & 15)) = 0;
    }

    // persistent A-frags (this wave's 32 rows x 320 K), coalesced frag loads
    bf16x8 a_f[20];
    {
        const u16* xp = xnf + ((size_t)m32 * 20 * 64 + lane) * 8;
        #pragma unroll
        for (int kk = 0; kk < 20; ++kk)
            a_f[kk] = *(const bf16x8*)(xp + kk * 512);
    }

    #define STAGE(hd_, c_) do {                                                        \
        const u16* gsrc_ = wqkv + ((size_t)((hd_) * 10 + (c_)) * 6144);                \
        u16* ldst_ = (u16*)smem + ((c_) % 3) * 6144;                                   \
        _Pragma("unroll")                                                              \
        for (int i_ = 0; i_ < 3; ++i_)                                                 \
            __builtin_amdgcn_global_load_lds(                                          \
                (const __attribute__((address_space(1))) void*)(gsrc_ + (tid + i_ * 256) * 8), \
                (__attribute__((address_space(3))) void*)(ldst_ + (tid + i_ * 256) * 8),       \
                16, 0, 0);                                                             \
    } while (0)

    for (int hd = 0; hd < NHEADS; ++hd){
        // prev head's attn reads of qh/kh done before staging clobbers them
        __builtin_amdgcn_sched_barrier(0);
        __builtin_amdgcn_s_barrier();
        __builtin_amdgcn_sched_barrier(0);

        STAGE(hd, 0);

        f32x16 acc[6];
        #pragma unroll
        for (int nb = 0; nb < 6; ++nb) acc[nb] = (f32x16)Z16;

        #pragma unroll
        for (int c = 0; c < 10; ++c){
            asm volatile("s_waitcnt vmcnt(0)" ::: "memory");
            __builtin_amdgcn_sched_barrier(0);
            __builtin_amdgcn_s_barrier();      // chunk c visible to all waves
            __builtin_amdgcn_sched_barrier(0);
            if (c < 9) STAGE(hd, c + 1);       // prefetch next chunk into buf[(c+1)%3]
            const u16* wb = (const u16*)smem + (c % 3) * 6144;
            #pragma unroll
            for (int kl = 0; kl < 2; ++kl){
                #pragma unroll
                for (int nb = 0; nb < 6; ++nb){
                    bf16x8 b = *(const bf16x8*)(wb + (nb * 2 + kl) * 512 + lane * 8);
                    acc[nb] = __builtin_amdgcn_mfma_f32_32x32x16_bf16(a_f[c * 2 + kl], b, acc[nb], 0, 0, 0);
                }
            }
            __builtin_amdgcn_sched_barrier(0);   // keep this chunk's ds_reads/MFMAs here
            // no trailing barrier: buf[(c+1)%3] being staged was last read at chunk c-2,
            // separated by the barriers at tops of c-1 and c.
        }
        __builtin_amdgcn_s_barrier();            // laggards done reading buf[0] (=qh) before unpack writes
        __builtin_amdgcn_sched_barrier(0);

        // ---- unpack QKV accumulators to wave-private LDS slices ----
        #pragma unroll
        for (int r = 0; r < 16; ++r){
            int row = (r & 3) + 8 * (r >> 2) + 4 * h32;   // verified 32x32 C layout
            int smp = row >> 4, tr = row & 15;
            QH(wid, smp, tr, l31)      = f2bf(acc[0][r] * 0.125f);   // pre-scale 1/sqrt(64)
            QH(wid, smp, tr, 32 + l31) = f2bf(acc[1][r] * 0.125f);
            KH(wid, smp, tr, l31)      = f2bf(acc[2][r]);
            KH(wid, smp, tr, 32 + l31) = f2bf(acc[3][r]);
            VT(wid, smp, l31, tr)      = f2bf(acc[4][r]);            // V^T: [d][key16]
            VT(wid, smp, 32 + l31, tr) = f2bf(acc[5][r]);
        }

        // ---- attention, per owned sample (wave-private) ----
        #pragma unroll
        for (int smp = 0; smp < 2; ++smp){
            f32x4 sc = zero4;
            #pragma unroll
            for (int k0 = 0; k0 < DH; k0 += 32){
                bf16x8 qa = *(const bf16x8*)&QH(wid, smp, l15, k0 + g4 * 8);
                bf16x8 kb = *(const bf16x8*)&KH(wid, smp, l15, k0 + g4 * 8);
                sc = __builtin_amdgcn_mfma_f32_16x16x32_bf16(qa, kb, sc, 0, 0, 0);
            }
            f32x4 pr;
            #pragma unroll
            for (int r = 0; r < 4; ++r){
                float m = sc[r];
                m = fmaxf(m, __shfl_xor(m, 1)); m = fmaxf(m, __shfl_xor(m, 2));
                m = fmaxf(m, __shfl_xor(m, 4)); m = fmaxf(m, __shfl_xor(m, 8));
                float e = __expf(sc[r] - m);
                float ss = e;
                ss += __shfl_xor(ss, 1); ss += __shfl_xor(ss, 2);
                ss += __shfl_xor(ss, 4); ss += __shfl_xor(ss, 8);
                pr[r] = e / ss;
            }
            // P -> qh cols 0..31 (Q dead); keys 16..31 zero
            #pragma unroll
            for (int r = 0; r < 4; ++r){
                QH(wid, smp, g4 * 4 + r, l15) = f2bf(pr[r]);
                QH(wid, smp, g4 * 4 + r, 16 + l15) = 0;
            }
            // PV (K=32 zero-padded), stage into kh (dead after scores)
            bf16x8 pa = *(const bf16x8*)&QH(wid, smp, l15, g4 * 8);
            #pragma unroll
            for (int nb = 0; nb < 4; ++nb){
                bf16x8 vb = *(const bf16x8*)&VT(wid, smp, nb * 16 + l15, g4 * 8);
                f32x4 at = __builtin_amdgcn_mfma_f32_16x16x32_bf16(pa, vb, zero4, 0, 0, 0);
                #pragma unroll
                for (int r = 0; r < 4; ++r)
                    KH(wid, smp, g4 * 4 + r, nb * 16 + l15) = f2bf(at[r]);
            }
            // store attn-out to aot[t][sample][k]: 16 x 64B segments per store op
            const size_t sg = (size_t)m32 * 2 + smp;
            #pragma unroll
            for (int kkl = 0; kkl < 2; ++kkl){
                bf16x8 o8 = *(const bf16x8*)&KH(wid, smp, l15, kkl * 32 + g4 * 8);
                *(bf16x8*)(aot + ((size_t)l15 * 4096 + sg) * 512 + hd * 64 + kkl * 32 + g4 * 8) = o8;
            }
        }
    }
    #undef STAGE
}

// ---------------- kernel 4: fused O-proj + bias + residual + transpose-out ----------------
__global__ __launch_bounds__(256) void k_oproj_res(const u16* __restrict__ aot, const u16* __restrict__ wof,
                                                   const float* __restrict__ bo, const float* __restrict__ x,
                                                   float* __restrict__ out){
    __shared__ u16 atile[32 * 516];       // [sample][k], row stride 516 (2-way-free)
    __shared__ float otile[4][32 * 36];   // per-wave [c][w], row stride 36

    const int tid  = threadIdx.x;
    const int lane = tid & 63;
    const int wid  = tid >> 6;            // 0..3
    const int l31  = lane & 31;
    const int h32  = lane >> 5;
    int wg = blockIdx.x;                  // (b,h,t)
    int t = wg & 15, h = (wg >> 4) & 31, b = wg >> 9;
    const int s0 = (b * 32 + h) * 32;

    // stage A: 32 rows x 512 (32KB contiguous in aot) -> padded LDS (reg-staged)
    {
        const u16* src = aot + ((size_t)t * 4096 + s0) * 512;
        #pragma unroll
        for (int i = 0; i < 8; ++i){
            int flat = tid + 256 * i;          // 0..2047
            int row = flat >> 6, c16 = flat & 63;
            bf16x8 v = *(const bf16x8*)(src + (size_t)flat * 8);
            *(bf16x8*)(atile + row * 516 + c16 * 8) = v;
        }
    }
    __syncthreads();

    // wave's c-block range: 3/3/2/2
    const int nb_start = (wid < 2) ? wid * 3 : 6 + (wid - 2) * 2;
    const int nb_count = (wid < 2) ? 3 : 2;

    for (int j = 0; j < nb_count; ++j){
        const int nb = nb_start + j;
        f32x16 acc = (f32x16)Z16;
        const u16* wp = wof + ((size_t)(nb * 32) * 64 + lane) * 8;
        #pragma unroll
        for (int kt = 0; kt < 32; ++kt){
            bf16x8 af = *(const bf16x8*)(atile + l31 * 516 + kt * 16 + h32 * 8);
            bf16x8 bf = *(const bf16x8*)(wp + (size_t)kt * 512);
            acc = __builtin_amdgcn_mfma_f32_32x32x16_bf16(af, bf, acc, 0, 0, 0);
        }
        // C layout: col = l31 (c within block), row = (r&3)+8*(r>>2)+4*h32 (= w)
        float bias_v = bo[nb * 32 + l31];
        #pragma unroll
        for (int r = 0; r < 16; ++r){
            int row = (r & 3) + 8 * (r >> 2) + 4 * h32;
            otile[wid][l31 * 36 + row] = acc[r] + bias_v;
        }
        // residual + coalesced float4 write along w (same wave; compiler orders LDS RAW)
        int cl = lane >> 3;                   // 0..7
        int w4 = (lane & 7) * 4;
        #pragma unroll
        for (int ci = 0; ci < 4; ++ci){
            int c = ci * 8 + cl;
            size_t idx = ((size_t)(b * CC + nb * 32 + c) * TT + t) * 1024 + h * 32 + w4;
            f32x4 ov = *(const f32x4*)(&otile[wid][c * 36 + w4]);
            f32x4 xv = *(const f32x4*)(x + idx);
            *(f32x4*)(out + idx) = xv + ov;
        }
    }
}

extern "C" void kernel_launch(void* const* d_in, const int* in_sizes, int n_in,
                              void* d_out, int out_size, void* d_ws, size_t ws_size,
                              hipStream_t stream){
    const float* hid = (const float*)d_in[0];
    const float* lnw = (const float*)d_in[1];
    const float* lnb = (const float*)d_in[2];
    const float* Wq  = (const float*)d_in[3];
    const float* Wk  = (const float*)d_in[4];
    const float* Wv  = (const float*)d_in[5];
    const float* Wo  = (const float*)d_in[6];
    const float* bo  = (const float*)d_in[7];

    char* ws = (char*)d_ws;
    u16* wqkv = (u16*)ws;                                   // 960 frags * 512 = 491,520 elems
    u16* wo_f = wqkv + (size_t)960 * 512;                   // 320 frags * 512 = 163,840 elems
    u16* aot  = wo_f + 163840;                              // 16*4096*512 (67 MB), [t][sample][k]
    u16* xn   = aot + (size_t)TT * 4096 * INNER;            // 65536*320 (40 MB), 32-frag-major

    k_wprep    <<<320, 256, 0, stream>>>(Wq, Wk, Wv, Wo, wqkv, wo_f);
    k_ln       <<<2048, 256, 0, stream>>>(hid, lnw, lnb, xn);
    k_attn     <<<512, 256, 0, stream>>>(xn, wqkv, aot);
    k_oproj_res<<<2048, 256, 0, stream>>>(aot, wo_f, bo, hid, (float*)d_out);
}

// Round 15
// 199.978 us; speedup vs baseline: 1.9519x; 1.0516x over previous
//
#include <hip/hip_runtime.h>

#define TT 16
#define CC 320
#define NHEADS 8
#define DH 64
#define INNER 512

typedef float f32x4 __attribute__((ext_vector_type(4)));
typedef float f32x16 __attribute__((ext_vector_type(16)));
typedef short bf16x8 __attribute__((ext_vector_type(8)));
typedef unsigned short u16;

#define Z16 {0.f,0.f,0.f,0.f,0.f,0.f,0.f,0.f,0.f,0.f,0.f,0.f,0.f,0.f,0.f,0.f}

__device__ __forceinline__ float bf2f(u16 u){
    union { unsigned int i; float f; } v; v.i = ((unsigned int)u) << 16; return v.f;
}
__device__ __forceinline__ u16 f2bf(float f){
    union { float f; unsigned int i; } v; v.f = f;
    unsigned int x = v.i;
    return (u16)((x + 0x7fffu + ((x >> 16) & 1u)) >> 16);   // RNE
}

// ---------------- kernel 1: merged prep (weight frags + LayerNorm) ----------------
// blk <  240 : Wq/Wk/Wv -> bf16 32x32x16-frag, 24KB-CHUNK-major (R6 layout):
//              frag f = ((hd*5 + c)*6 + nblk)*4 + kl ; kk = c*4 + kl
//              nblk 0,1=Q 2,3=K 4,5=V. lane = ((k%16)>>3)*32 + (n%32), elem=k%8.
// blk <  320 : Wo -> bf16 32x32x16-frag-major: frag f = nb*32 + kt.
// blk >= 320 : transpose + LayerNorm -> xn bf16 32x32x16 A-frag-major (wg = blk-320).
__global__ __launch_bounds__(256) void k_prep(const float* __restrict__ wq, const float* __restrict__ wk,
                                              const float* __restrict__ wv, const float* __restrict__ wo,
                                              const float* __restrict__ lnw, const float* __restrict__ lnb,
                                              const float* __restrict__ x,
                                              u16* __restrict__ dqkv, u16* __restrict__ dwo,
                                              u16* __restrict__ xnf){
    __shared__ float tile[CC][37];
    __shared__ float psum[32][36];
    __shared__ float psq[32][36];
    __shared__ float meanb[32];
    __shared__ float rstdb[32];
    __shared__ float lnw_s[CC];
    __shared__ float lnb_s[CC];

    int blk = blockIdx.x;
    int tid = threadIdx.x;

    if (blk < 240){
        int gid  = blk * 256 + tid;                   // 0..61439
        int lane = gid & 63;
        int f    = gid >> 6;                          // 0..959
        int kl   = f & 3;
        int nblk = (f >> 2) % 6;
        int c    = ((f >> 2) / 6) % 5;
        int hd   = f / 120;
        int kk   = c * 4 + kl;
        const float* W = (nblk < 2) ? wq : (nblk < 4) ? wk : wv;
        int n  = hd * DH + (nblk & 1) * 32 + (lane & 31);
        int k0 = kk * 16 + (lane >> 5) * 8;
        const float* src = W + (size_t)n * CC + k0;
        f32x4 v0 = *(const f32x4*)src;
        f32x4 v1 = *(const f32x4*)(src + 4);
        bf16x8 o;
        o[0] = (short)f2bf(v0[0]); o[1] = (short)f2bf(v0[1]);
        o[2] = (short)f2bf(v0[2]); o[3] = (short)f2bf(v0[3]);
        o[4] = (short)f2bf(v1[0]); o[5] = (short)f2bf(v1[1]);
        o[6] = (short)f2bf(v1[2]); o[7] = (short)f2bf(v1[3]);
        *(bf16x8*)(dqkv + (size_t)gid * 8) = o;
        return;
    }
    if (blk < 320){
        int gid  = (blk - 240) * 256 + tid;           // 0..20479
        int lane = gid & 63;
        int f    = gid >> 6;                          // 0..319
        int kt   = f & 31;
        int nb   = f >> 5;
        int n  = nb * 32 + (lane & 31);
        int k0 = kt * 16 + (lane >> 5) * 8;
        const float* src = wo + (size_t)n * INNER + k0;
        f32x4 v0 = *(const f32x4*)src;
        f32x4 v1 = *(const f32x4*)(src + 4);
        bf16x8 o;
        o[0] = (short)f2bf(v0[0]); o[1] = (short)f2bf(v0[1]);
        o[2] = (short)f2bf(v0[2]); o[3] = (short)f2bf(v0[3]);
        o[4] = (short)f2bf(v1[0]); o[5] = (short)f2bf(v1[1]);
        o[6] = (short)f2bf(v1[2]); o[7] = (short)f2bf(v1[3]);
        *(bf16x8*)(dwo + (size_t)gid * 8) = o;
        return;
    }

    // ---- LayerNorm branch ----
    int wg = blk - 320;                  // (b,h,t)
    int t = wg & 15, h = (wg >> 4) & 31, b = wg >> 9;
    const size_t base = ((size_t)(b * CC) * TT + t) * 1024 + h * 32;

    if (tid < CC - 256){ lnw_s[256 + tid] = lnw[256 + tid]; lnb_s[256 + tid] = lnb[256 + tid]; }
    lnw_s[tid] = lnw[tid]; lnb_s[tid] = lnb[tid];

    int w4 = (tid & 7) * 4, cg = tid >> 3;
    f32x4 s4 = {0.f,0.f,0.f,0.f}, q4 = {0.f,0.f,0.f,0.f};
    for (int i = 0; i < 10; ++i){
        int c = cg * 10 + i;
        f32x4 v = *(const f32x4*)(x + base + (size_t)c * 16384 + w4);
        tile[c][w4 + 0] = v[0]; tile[c][w4 + 1] = v[1];
        tile[c][w4 + 2] = v[2]; tile[c][w4 + 3] = v[3];
        s4 += v; q4 += v * v;
    }
    psum[cg][w4 + 0] = s4[0]; psum[cg][w4 + 1] = s4[1]; psum[cg][w4 + 2] = s4[2]; psum[cg][w4 + 3] = s4[3];
    psq [cg][w4 + 0] = q4[0]; psq [cg][w4 + 1] = q4[1]; psq [cg][w4 + 2] = q4[2]; psq [cg][w4 + 3] = q4[3];
    __syncthreads();

    if (tid < 32){
        float s = 0.f, q = 0.f;
        for (int g = 0; g < 32; ++g){ s += psum[g][tid]; q += psq[g][tid]; }
        float mean = s * (1.f / CC);
        float var  = q * (1.f / CC) - mean * mean;
        meanb[tid] = mean;
        rstdb[tid] = rsqrtf(var + 1e-5f);
    }
    __syncthreads();

    int s_base = (b * 32 + h) * 32;
    #pragma unroll
    for (int j = 0; j < 5; ++j){
        int u = tid + 256 * j;              // 0..1279
        int w = u / 40, c8 = u % 40;
        float mean = meanb[w], rstd = rstdb[w];
        int s = s_base + w;
        int row = ((s & 1) << 4) | t;
        int kk = c8 >> 1;
        int lane_f = ((c8 & 1) << 5) | row;
        size_t m32 = (size_t)(s >> 1);
        bf16x8 o;
        #pragma unroll
        for (int e = 0; e < 8; ++e){
            int c = c8 * 8 + e;
            float nv = (tile[c][w] - mean) * rstd * lnw_s[c] + lnb_s[c];
            o[e] = (short)f2bf(nv);
        }
        *(bf16x8*)(xnf + ((size_t)(m32 * 20 + kk) * 64 + lane_f) * 8) = o;
    }
}

// ---------------- kernel 2: fused QKV + attention — R6-EXACT structure (best: 100us) ----------------
// 512 thr = 8 waves; wave owns one 32-row m-tile (2 samples), xn A-frags in regs.
// Per head: 5 chunks of 24KB staged via global_load_lds (double-buffered, overlaying
// qh/kh scratch which is fully rewritten per head; vt with persistent zero-pads NOT
// overlaid). Attention: per-sample 16x16 path. LDS 144KB -> 1 WG/CU.
// ONLY change vs R6: attn-out store layout -> aot[t][sample][k] (verified cost-free, R13).
#define QH(w,s,r,c) smem[((((w)*2+(s))*16+(r))*72) + (c)]
#define KH(w,s,r,c) smem[18432 + ((((w)*2+(s))*16+(r))*72) + (c)]
#define VT(w,s,d,k) smem[36864 + ((((w)*2+(s))*64+(d))*36) + (k)]

__global__ __launch_bounds__(512, 2) void k_attn(const u16* __restrict__ xnf,
                                                 const u16* __restrict__ wqkv,
                                                 u16* __restrict__ aot){
    // 144 KB: qh[0..18431] kh[18432..36863] vt[36864..73727] (u16 indices)
    // weight buffers overlay: buf0 = smem[0..12287], buf1 = smem[12288..24575]
    __shared__ u16 smem[73728];

    const int tid  = threadIdx.x;
    const int lane = tid & 63;
    const int wid  = tid >> 6;        // 0..7
    const int l31  = lane & 31;
    const int h32  = lane >> 5;
    const int l15  = lane & 15;
    const int g4   = lane >> 4;
    const int m32  = blockIdx.x * 8 + wid;
    const f32x4 zero4 = {0.f, 0.f, 0.f, 0.f};

    // zero vt pad cols 16..31 once (vt region is NOT overlaid by weight buffers)
    #pragma unroll
    for (int j = 0; j < 32; ++j){
        int idx = j * 64 + lane;           // 0..2047 per wave slice
        int smp = idx >> 10;
        int d   = (idx >> 4) & 63;
        VT(wid, smp, d, 16 + (idx & 15)) = 0;
    }

    // persistent A-frags (this wave's 32 rows x 320 K), coalesced frag loads
    bf16x8 a_f[20];
    {
        const u16* xp = xnf + ((size_t)m32 * 20 * 64 + lane) * 8;
        #pragma unroll
        for (int kk = 0; kk < 20; ++kk)
            a_f[kk] = *(const bf16x8*)(xp + kk * 512);
    }

    #define STAGE(hd_, c_) do {                                                        \
        const u16* gsrc_ = wqkv + ((size_t)((hd_) * 5 + (c_)) * 12288);                \
        u16* ldst_ = (u16*)smem + ((c_) & 1) * 12288;                                  \
        _Pragma("unroll")                                                              \
        for (int i_ = 0; i_ < 3; ++i_)                                                 \
            __builtin_amdgcn_global_load_lds(                                          \
                (const __attribute__((address_space(1))) void*)(gsrc_ + (tid + i_ * 512) * 8), \
                (__attribute__((address_space(3))) void*)(ldst_ + (tid + i_ * 512) * 8),       \
                16, 0, 0);                                                             \
    } while (0)

    for (int hd = 0; hd < NHEADS; ++hd){
        // all waves done reading qh/kh (attn of prev head) before staging clobbers them
        __builtin_amdgcn_sched_barrier(0);
        __builtin_amdgcn_s_barrier();
        __builtin_amdgcn_sched_barrier(0);

        STAGE(hd, 0);

        f32x16 acc[6];
        #pragma unroll
        for (int nb = 0; nb < 6; ++nb) acc[nb] = (f32x16)Z16;

        #pragma unroll
        for (int c = 0; c < 5; ++c){
            // drain staging (chunk c landed; cheap after first iter since it flew during compute c-1)
            asm volatile("s_waitcnt vmcnt(0)" ::: "memory");
            __builtin_amdgcn_sched_barrier(0);
            __builtin_amdgcn_s_barrier();      // chunk c visible from all waves
            __builtin_amdgcn_sched_barrier(0);
            if (c < 4) STAGE(hd, c + 1);       // prefetch next chunk during compute
            const u16* wb = (const u16*)smem + (c & 1) * 12288;
            #pragma unroll
            for (int kl = 0; kl < 4; ++kl){
                #pragma unroll
                for (int nb = 0; nb < 6; ++nb){
                    bf16x8 b = *(const bf16x8*)(wb + (nb * 4 + kl) * 512 + lane * 8);
                    acc[nb] = __builtin_amdgcn_mfma_f32_32x32x16_bf16(a_f[c * 4 + kl], b, acc[nb], 0, 0, 0);
                }
            }
            __builtin_amdgcn_sched_barrier(0);
            __builtin_amdgcn_s_barrier();      // all waves done reading buf[c&1]
            __builtin_amdgcn_sched_barrier(0);
        }

        // ---- unpack QKV accumulators to wave-private LDS slices ----
        #pragma unroll
        for (int r = 0; r < 16; ++r){
            int row = (r & 3) + 8 * (r >> 2) + 4 * h32;   // verified 32x32 C layout
            int smp = row >> 4, tr = row & 15;
            QH(wid, smp, tr, l31)      = f2bf(acc[0][r] * 0.125f);   // pre-scale 1/sqrt(64)
            QH(wid, smp, tr, 32 + l31) = f2bf(acc[1][r] * 0.125f);
            KH(wid, smp, tr, l31)      = f2bf(acc[2][r]);
            KH(wid, smp, tr, 32 + l31) = f2bf(acc[3][r]);
            VT(wid, smp, l31, tr)      = f2bf(acc[4][r]);            // V^T: [d][key16]
            VT(wid, smp, 32 + l31, tr) = f2bf(acc[5][r]);
        }

        // ---- attention, per owned sample (wave-private, no barriers) ----
        #pragma unroll
        for (int smp = 0; smp < 2; ++smp){
            f32x4 sc = zero4;
            #pragma unroll
            for (int k0 = 0; k0 < DH; k0 += 32){
                bf16x8 qa = *(const bf16x8*)&QH(wid, smp, l15, k0 + g4 * 8);
                bf16x8 kb = *(const bf16x8*)&KH(wid, smp, l15, k0 + g4 * 8);
                sc = __builtin_amdgcn_mfma_f32_16x16x32_bf16(qa, kb, sc, 0, 0, 0);
            }
            f32x4 pr;
            #pragma unroll
            for (int r = 0; r < 4; ++r){
                float m = sc[r];
                m = fmaxf(m, __shfl_xor(m, 1)); m = fmaxf(m, __shfl_xor(m, 2));
                m = fmaxf(m, __shfl_xor(m, 4)); m = fmaxf(m, __shfl_xor(m, 8));
                float e = __expf(sc[r] - m);
                float ss = e;
                ss += __shfl_xor(ss, 1); ss += __shfl_xor(ss, 2);
                ss += __shfl_xor(ss, 4); ss += __shfl_xor(ss, 8);
                pr[r] = e / ss;
            }
            // P -> qh cols 0..31 (Q dead); keys 16..31 zero
            #pragma unroll
            for (int r = 0; r < 4; ++r){
                QH(wid, smp, g4 * 4 + r, l15) = f2bf(pr[r]);
                QH(wid, smp, g4 * 4 + r, 16 + l15) = 0;
            }
            // PV (K=32 zero-padded), stage into kh (dead after scores)
            bf16x8 pa = *(const bf16x8*)&QH(wid, smp, l15, g4 * 8);
            #pragma unroll
            for (int nb = 0; nb < 4; ++nb){
                bf16x8 vb = *(const bf16x8*)&VT(wid, smp, nb * 16 + l15, g4 * 8);
                f32x4 at = __builtin_amdgcn_mfma_f32_16x16x32_bf16(pa, vb, zero4, 0, 0, 0);
                #pragma unroll
                for (int r = 0; r < 4; ++r)
                    KH(wid, smp, g4 * 4 + r, nb * 16 + l15) = f2bf(at[r]);
            }
            // store attn-out to aot[t][sample][k]: 16 x 64B segments per store op
            const size_t sg = (size_t)m32 * 2 + smp;
            #pragma unroll
            for (int kkl = 0; kkl < 2; ++kkl){
                bf16x8 o8 = *(const bf16x8*)&KH(wid, smp, l15, kkl * 32 + g4 * 8);
                *(bf16x8*)(aot + ((size_t)l15 * 4096 + sg) * 512 + hd * 64 + kkl * 32 + g4 * 8) = o8;
            }
        }
    }
    #undef STAGE
}

// ---------------- kernel 3: fused O-proj + bias + residual + transpose-out ----------------
__global__ __launch_bounds__(256) void k_oproj_res(const u16* __restrict__ aot, const u16* __restrict__ wof,
                                                   const float* __restrict__ bo, const float* __restrict__ x,
                                                   float* __restrict__ out){
    __shared__ u16 atile[32 * 516];       // [sample][k], row stride 516 (2-way-free)
    __shared__ float otile[4][32 * 36];   // per-wave [c][w], row stride 36

    const int tid  = threadIdx.x;
    const int lane = tid & 63;
    const int wid  = tid >> 6;            // 0..3
    const int l31  = lane & 31;
    const int h32  = lane >> 5;
    int wg = blockIdx.x;                  // (b,h,t)
    int t = wg & 15, h = (wg >> 4) & 31, b = wg >> 9;
    const int s0 = (b * 32 + h) * 32;

    // stage A: 32 rows x 512 (32KB contiguous in aot) -> padded LDS (reg-staged)
    {
        const u16* src = aot + ((size_t)t * 4096 + s0) * 512;
        #pragma unroll
        for (int i = 0; i < 8; ++i){
            int flat = tid + 256 * i;          // 0..2047
            int row = flat >> 6, c16 = flat & 63;
            bf16x8 v = *(const bf16x8*)(src + (size_t)flat * 8);
            *(bf16x8*)(atile + row * 516 + c16 * 8) = v;
        }
    }
    __syncthreads();

    // wave's c-block range: 3/3/2/2
    const int nb_start = (wid < 2) ? wid * 3 : 6 + (wid - 2) * 2;
    const int nb_count = (wid < 2) ? 3 : 2;

    for (int j = 0; j < nb_count; ++j){
        const int nb = nb_start + j;
        f32x16 acc = (f32x16)Z16;
        const u16* wp = wof + ((size_t)(nb * 32) * 64 + lane) * 8;
        #pragma unroll
        for (int kt = 0; kt < 32; ++kt){
            bf16x8 af = *(const bf16x8*)(atile + l31 * 516 + kt * 16 + h32 * 8);
            bf16x8 bf = *(const bf16x8*)(wp + (size_t)kt * 512);
            acc = __builtin_amdgcn_mfma_f32_32x32x16_bf16(af, bf, acc, 0, 0, 0);
        }
        // C layout: col = l31 (c within block), row = (r&3)+8*(r>>2)+4*h32 (= w)
        float bias_v = bo[nb * 32 + l31];
        #pragma unroll
        for (int r = 0; r < 16; ++r){
            int row = (r & 3) + 8 * (r >> 2) + 4 * h32;
            otile[wid][l31 * 36 + row] = acc[r] + bias_v;
        }
        // residual + coalesced float4 write along w (same wave; compiler orders LDS RAW)
        int cl = lane >> 3;                   // 0..7
        int w4 = (lane & 7) * 4;
        #pragma unroll
        for (int ci = 0; ci < 4; ++ci){
            int c = ci * 8 + cl;
            size_t idx = ((size_t)(b * CC + nb * 32 + c) * TT + t) * 1024 + h * 32 + w4;
            f32x4 ov = *(const f32x4*)(&otile[wid][c * 36 + w4]);
            f32x4 xv = *(const f32x4*)(x + idx);
            *(f32x4*)(out + idx) = xv + ov;
        }
    }
}

extern "C" void kernel_launch(void* const* d_in, const int* in_sizes, int n_in,
                              void* d_out, int out_size, void* d_ws, size_t ws_size,
                              hipStream_t stream){
    const float* hid = (const float*)d_in[0];
    const float* lnw = (const float*)d_in[1];
    const float* lnb = (const float*)d_in[2];
    const float* Wq  = (const float*)d_in[3];
    const float* Wk  = (const float*)d_in[4];
    const float* Wv  = (const float*)d_in[5];
    const float* Wo  = (const float*)d_in[6];
    const float* bo  = (const float*)d_in[7];

    char* ws = (char*)d_ws;
    u16* wqkv = (u16*)ws;                                   // 960 frags * 512 = 491,520 elems
    u16* wo_f = wqkv + (size_t)960 * 512;                   // 320 frags * 512 = 163,840 elems
    u16* aot  = wo_f + 163840;                              // 16*4096*512 (67 MB), [t][sample][k]
    u16* xn   = aot + (size_t)TT * 4096 * INNER;            // 65536*320 (40 MB), 32-frag-major

    k_prep     <<<2368, 256, 0, stream>>>(Wq, Wk, Wv, Wo, lnw, lnb, hid, wqkv, wo_f, xn);
    k_attn     <<<256, 512, 0, stream>>>(xn, wqkv, aot);
    k_oproj_res<<<2048, 256, 0, stream>>>(aot, wo_f, bo, hid, (float*)d_out);
}

// Round 16
// 197.868 us; speedup vs baseline: 1.9727x; 1.0107x over previous
//
#include <hip/hip_runtime.h>

#define TT 16
#define CC 320
#define NHEADS 8
#define DH 64
#define INNER 512

typedef float f32x4 __attribute__((ext_vector_type(4)));
typedef float f32x16 __attribute__((ext_vector_type(16)));
typedef short bf16x8 __attribute__((ext_vector_type(8)));
typedef unsigned short u16;

#define Z16 {0.f,0.f,0.f,0.f,0.f,0.f,0.f,0.f,0.f,0.f,0.f,0.f,0.f,0.f,0.f,0.f}

__device__ __forceinline__ float bf2f(u16 u){
    union { unsigned int i; float f; } v; v.i = ((unsigned int)u) << 16; return v.f;
}
__device__ __forceinline__ u16 f2bf(float f){
    union { float f; unsigned int i; } v; v.f = f;
    unsigned int x = v.i;
    return (u16)((x + 0x7fffu + ((x >> 16) & 1u)) >> 16);   // RNE
}

// ---------------- kernel 1: merged prep (weight frags + LayerNorm) ----------------
// blk <  240 : Wq/Wk/Wv -> bf16 32x32x16-frag, 24KB-CHUNK-major (R6 layout):
//              frag f = ((hd*5 + c)*6 + nblk)*4 + kl ; kk = c*4 + kl
//              nblk 0,1=Q 2,3=K 4,5=V. lane = ((k%16)>>3)*32 + (n%32), elem=k%8.
// blk <  320 : Wo -> bf16 32x32x16-frag-major: frag f = nb*32 + kt.
// blk >= 320 : transpose + LayerNorm -> xn bf16 32x32x16 A-frag-major (wg = blk-320).
__global__ __launch_bounds__(256) void k_prep(const float* __restrict__ wq, const float* __restrict__ wk,
                                              const float* __restrict__ wv, const float* __restrict__ wo,
                                              const float* __restrict__ lnw, const float* __restrict__ lnb,
                                              const float* __restrict__ x,
                                              u16* __restrict__ dqkv, u16* __restrict__ dwo,
                                              u16* __restrict__ xnf){
    __shared__ float tile[CC][37];
    __shared__ float psum[32][36];
    __shared__ float psq[32][36];
    __shared__ float meanb[32];
    __shared__ float rstdb[32];
    __shared__ float lnw_s[CC];
    __shared__ float lnb_s[CC];

    int blk = blockIdx.x;
    int tid = threadIdx.x;

    if (blk < 240){
        int gid  = blk * 256 + tid;                   // 0..61439
        int lane = gid & 63;
        int f    = gid >> 6;                          // 0..959
        int kl   = f & 3;
        int nblk = (f >> 2) % 6;
        int c    = ((f >> 2) / 6) % 5;
        int hd   = f / 120;
        int kk   = c * 4 + kl;
        const float* W = (nblk < 2) ? wq : (nblk < 4) ? wk : wv;
        int n  = hd * DH + (nblk & 1) * 32 + (lane & 31);
        int k0 = kk * 16 + (lane >> 5) * 8;
        const float* src = W + (size_t)n * CC + k0;
        f32x4 v0 = *(const f32x4*)src;
        f32x4 v1 = *(const f32x4*)(src + 4);
        bf16x8 o;
        o[0] = (short)f2bf(v0[0]); o[1] = (short)f2bf(v0[1]);
        o[2] = (short)f2bf(v0[2]); o[3] = (short)f2bf(v0[3]);
        o[4] = (short)f2bf(v1[0]); o[5] = (short)f2bf(v1[1]);
        o[6] = (short)f2bf(v1[2]); o[7] = (short)f2bf(v1[3]);
        *(bf16x8*)(dqkv + (size_t)gid * 8) = o;
        return;
    }
    if (blk < 320){
        int gid  = (blk - 240) * 256 + tid;           // 0..20479
        int lane = gid & 63;
        int f    = gid >> 6;                          // 0..319
        int kt   = f & 31;
        int nb   = f >> 5;
        int n  = nb * 32 + (lane & 31);
        int k0 = kt * 16 + (lane >> 5) * 8;
        const float* src = wo + (size_t)n * INNER + k0;
        f32x4 v0 = *(const f32x4*)src;
        f32x4 v1 = *(const f32x4*)(src + 4);
        bf16x8 o;
        o[0] = (short)f2bf(v0[0]); o[1] = (short)f2bf(v0[1]);
        o[2] = (short)f2bf(v0[2]); o[3] = (short)f2bf(v0[3]);
        o[4] = (short)f2bf(v1[0]); o[5] = (short)f2bf(v1[1]);
        o[6] = (short)f2bf(v1[2]); o[7] = (short)f2bf(v1[3]);
        *(bf16x8*)(dwo + (size_t)gid * 8) = o;
        return;
    }

    // ---- LayerNorm branch ----
    int wg = blk - 320;                  // (b,h,t)
    int t = wg & 15, h = (wg >> 4) & 31, b = wg >> 9;
    const size_t base = ((size_t)(b * CC) * TT + t) * 1024 + h * 32;

    if (tid < CC - 256){ lnw_s[256 + tid] = lnw[256 + tid]; lnb_s[256 + tid] = lnb[256 + tid]; }
    lnw_s[tid] = lnw[tid]; lnb_s[tid] = lnb[tid];

    int w4 = (tid & 7) * 4, cg = tid >> 3;
    f32x4 s4 = {0.f,0.f,0.f,0.f}, q4 = {0.f,0.f,0.f,0.f};
    for (int i = 0; i < 10; ++i){
        int c = cg * 10 + i;
        f32x4 v = *(const f32x4*)(x + base + (size_t)c * 16384 + w4);
        tile[c][w4 + 0] = v[0]; tile[c][w4 + 1] = v[1];
        tile[c][w4 + 2] = v[2]; tile[c][w4 + 3] = v[3];
        s4 += v; q4 += v * v;
    }
    psum[cg][w4 + 0] = s4[0]; psum[cg][w4 + 1] = s4[1]; psum[cg][w4 + 2] = s4[2]; psum[cg][w4 + 3] = s4[3];
    psq [cg][w4 + 0] = q4[0]; psq [cg][w4 + 1] = q4[1]; psq [cg][w4 + 2] = q4[2]; psq [cg][w4 + 3] = q4[3];
    __syncthreads();

    if (tid < 32){
        float s = 0.f, q = 0.f;
        for (int g = 0; g < 32; ++g){ s += psum[g][tid]; q += psq[g][tid]; }
        float mean = s * (1.f / CC);
        float var  = q * (1.f / CC) - mean * mean;
        meanb[tid] = mean;
        rstdb[tid] = rsqrtf(var + 1e-5f);
    }
    __syncthreads();

    int s_base = (b * 32 + h) * 32;
    #pragma unroll
    for (int j = 0; j < 5; ++j){
        int u = tid + 256 * j;              // 0..1279
        int w = u / 40, c8 = u % 40;
        float mean = meanb[w], rstd = rstdb[w];
        int s = s_base + w;
        int row = ((s & 1) << 4) | t;
        int kk = c8 >> 1;
        int lane_f = ((c8 & 1) << 5) | row;
        size_t m32 = (size_t)(s >> 1);
        bf16x8 o;
        #pragma unroll
        for (int e = 0; e < 8; ++e){
            int c = c8 * 8 + e;
            float nv = (tile[c][w] - mean) * rstd * lnw_s[c] + lnb_s[c];
            o[e] = (short)f2bf(nv);
        }
        *(bf16x8*)(xnf + ((size_t)(m32 * 20 + kk) * 64 + lane_f) * 8) = o;
    }
}

// ---------------- kernel 2: fused QKV + attention — R6 structure + chunk-0 prefetch buffer ----------------
// 512 thr = 8 waves; wave owns one 32-row m-tile (2 samples), xn A-frags in regs.
// Per head: 5 chunks of 24KB. NEW: chunk 0 of head hd+1 is prefetched into a dedicated
// 12KB pbuf during head hd's attention phase (pbuf overlaps nothing); chunks 1..4
// double-buffer in the qh/kh overlay as before (chunk c>=1 -> buf[(c+1)&1]).
// LDS 156KB -> 1 WG/CU. Math byte-identical to R15.
#define QH(w,s,r,c) smem[((((w)*2+(s))*16+(r))*72) + (c)]
#define KH(w,s,r,c) smem[18432 + ((((w)*2+(s))*16+(r))*72) + (c)]
#define VT(w,s,d,k) smem[36864 + ((((w)*2+(s))*64+(d))*36) + (k)]

__global__ __launch_bounds__(512, 2) void k_attn(const u16* __restrict__ xnf,
                                                 const u16* __restrict__ wqkv,
                                                 u16* __restrict__ aot){
    // u16 idx: qh [0,18432) kh [18432,36864) vt [36864,73728) pbuf [73728,79872)
    // weight double-buffer overlays qh+kh: buf0 = [0,12288), buf1 = [12288,24576)
    __shared__ u16 smem[79872];

    const int tid  = threadIdx.x;
    const int lane = tid & 63;
    const int wid  = tid >> 6;        // 0..7
    const int l31  = lane & 31;
    const int h32  = lane >> 5;
    const int l15  = lane & 15;
    const int g4   = lane >> 4;
    const int m32  = blockIdx.x * 8 + wid;
    const f32x4 zero4 = {0.f, 0.f, 0.f, 0.f};

    // zero vt pad cols 16..31 once (vt region never overlaid)
    #pragma unroll
    for (int j = 0; j < 32; ++j){
        int idx = j * 64 + lane;           // 0..2047 per wave slice
        int smp = idx >> 10;
        int d   = (idx >> 4) & 63;
        VT(wid, smp, d, 16 + (idx & 15)) = 0;
    }

    // stage: chunk c of head hd -> dst (u16* in LDS)
    #define STAGE_TO(hd_, c_, dst_) do {                                               \
        const u16* gsrc_ = wqkv + ((size_t)((hd_) * 5 + (c_)) * 12288);                \
        u16* ldst_ = (dst_);                                                           \
        _Pragma("unroll")                                                              \
        for (int i_ = 0; i_ < 3; ++i_)                                                 \
            __builtin_amdgcn_global_load_lds(                                          \
                (const __attribute__((address_space(1))) void*)(gsrc_ + (tid + i_ * 512) * 8), \
                (__attribute__((address_space(3))) void*)(ldst_ + (tid + i_ * 512) * 8),       \
                16, 0, 0);                                                             \
    } while (0)

    // prologue: prefetch head 0 chunk 0 into pbuf (flies during a_f loads)
    STAGE_TO(0, 0, (u16*)smem + 73728);

    // persistent A-frags (this wave's 32 rows x 320 K), coalesced frag loads
    bf16x8 a_f[20];
    {
        const u16* xp = xnf + ((size_t)m32 * 20 * 64 + lane) * 8;
        #pragma unroll
        for (int kk = 0; kk < 20; ++kk)
            a_f[kk] = *(const bf16x8*)(xp + kk * 512);
    }

    for (int hd = 0; hd < NHEADS; ++hd){
        // all waves done reading qh/kh (attn of prev head) before chunk>=1 staging clobbers them
        __builtin_amdgcn_sched_barrier(0);
        __builtin_amdgcn_s_barrier();
        __builtin_amdgcn_sched_barrier(0);

        f32x16 acc[6];
        #pragma unroll
        for (int nb = 0; nb < 6; ++nb) acc[nb] = (f32x16)Z16;

        #pragma unroll
        for (int c = 0; c < 5; ++c){
            // drain staging (chunk c landed long ago for c==0 via pbuf; during compute c-1 otherwise)
            asm volatile("s_waitcnt vmcnt(0)" ::: "memory");
            __builtin_amdgcn_sched_barrier(0);
            __builtin_amdgcn_s_barrier();      // chunk c visible from all waves
            __builtin_amdgcn_sched_barrier(0);
            if (c < 4) STAGE_TO(hd, c + 1, (u16*)smem + ((c + 1) & 1) * 12288);  // prefetch next chunk
            const u16* wb = (c == 0) ? (const u16*)smem + 73728
                                     : (const u16*)smem + (c & 1) * 12288;
            #pragma unroll
            for (int kl = 0; kl < 4; ++kl){
                #pragma unroll
                for (int nb = 0; nb < 6; ++nb){
                    bf16x8 b = *(const bf16x8*)(wb + (nb * 4 + kl) * 512 + lane * 8);
                    acc[nb] = __builtin_amdgcn_mfma_f32_32x32x16_bf16(a_f[c * 4 + kl], b, acc[nb], 0, 0, 0);
                }
            }
            __builtin_amdgcn_sched_barrier(0);
            __builtin_amdgcn_s_barrier();      // all waves done reading this chunk's buffer
            __builtin_amdgcn_sched_barrier(0);
        }

        // prefetch NEXT head's chunk 0 into pbuf — flies during unpack + attention
        if (hd < NHEADS - 1) STAGE_TO(hd + 1, 0, (u16*)smem + 73728);

        // ---- unpack QKV accumulators to wave-private LDS slices ----
        #pragma unroll
        for (int r = 0; r < 16; ++r){
            int row = (r & 3) + 8 * (r >> 2) + 4 * h32;   // verified 32x32 C layout
            int smp = row >> 4, tr = row & 15;
            QH(wid, smp, tr, l31)      = f2bf(acc[0][r] * 0.125f);   // pre-scale 1/sqrt(64)
            QH(wid, smp, tr, 32 + l31) = f2bf(acc[1][r] * 0.125f);
            KH(wid, smp, tr, l31)      = f2bf(acc[2][r]);
            KH(wid, smp, tr, 32 + l31) = f2bf(acc[3][r]);
            VT(wid, smp, l31, tr)      = f2bf(acc[4][r]);            // V^T: [d][key16]
            VT(wid, smp, 32 + l31, tr) = f2bf(acc[5][r]);
        }

        // ---- attention, per owned sample (wave-private, no barriers) ----
        #pragma unroll
        for (int smp = 0; smp < 2; ++smp){
            f32x4 sc = zero4;
            #pragma unroll
            for (int k0 = 0; k0 < DH; k0 += 32){
                bf16x8 qa = *(const bf16x8*)&QH(wid, smp, l15, k0 + g4 * 8);
                bf16x8 kb = *(const bf16x8*)&KH(wid, smp, l15, k0 + g4 * 8);
                sc = __builtin_amdgcn_mfma_f32_16x16x32_bf16(qa, kb, sc, 0, 0, 0);
            }
            f32x4 pr;
            #pragma unroll
            for (int r = 0; r < 4; ++r){
                float m = sc[r];
                m = fmaxf(m, __shfl_xor(m, 1)); m = fmaxf(m, __shfl_xor(m, 2));
                m = fmaxf(m, __shfl_xor(m, 4)); m = fmaxf(m, __shfl_xor(m, 8));
                float e = __expf(sc[r] - m);
                float ss = e;
                ss += __shfl_xor(ss, 1); ss += __shfl_xor(ss, 2);
                ss += __shfl_xor(ss, 4); ss += __shfl_xor(ss, 8);
                pr[r] = e / ss;
            }
            // P -> qh cols 0..31 (Q dead); keys 16..31 zero
            #pragma unroll
            for (int r = 0; r < 4; ++r){
                QH(wid, smp, g4 * 4 + r, l15) = f2bf(pr[r]);
                QH(wid, smp, g4 * 4 + r, 16 + l15) = 0;
            }
            // PV (K=32 zero-padded), stage into kh (dead after scores)
            bf16x8 pa = *(const bf16x8*)&QH(wid, smp, l15, g4 * 8);
            #pragma unroll
            for (int nb = 0; nb < 4; ++nb){
                bf16x8 vb = *(const bf16x8*)&VT(wid, smp, nb * 16 + l15, g4 * 8);
                f32x4 at = __builtin_amdgcn_mfma_f32_16x16x32_bf16(pa, vb, zero4, 0, 0, 0);
                #pragma unroll
                for (int r = 0; r < 4; ++r)
                    KH(wid, smp, g4 * 4 + r, nb * 16 + l15) = f2bf(at[r]);
            }
            // store attn-out to aot[t][sample][k]: 16 x 64B segments per store op
            const size_t sg = (size_t)m32 * 2 + smp;
            #pragma unroll
            for (int kkl = 0; kkl < 2; ++kkl){
                bf16x8 o8 = *(const bf16x8*)&KH(wid, smp, l15, kkl * 32 + g4 * 8);
                *(bf16x8*)(aot + ((size_t)l15 * 4096 + sg) * 512 + hd * 64 + kkl * 32 + g4 * 8) = o8;
            }
        }
    }
    #undef STAGE_TO
}

// ---------------- kernel 3: fused O-proj + bias + residual + transpose-out ----------------
__global__ __launch_bounds__(256) void k_oproj_res(const u16* __restrict__ aot, const u16* __restrict__ wof,
                                                   const float* __restrict__ bo, const float* __restrict__ x,
                                                   float* __restrict__ out){
    __shared__ u16 atile[32 * 516];       // [sample][k], row stride 516 (2-way-free)
    __shared__ float otile[4][32 * 36];   // per-wave [c][w], row stride 36

    const int tid  = threadIdx.x;
    const int lane = tid & 63;
    const int wid  = tid >> 6;            // 0..3
    const int l31  = lane & 31;
    const int h32  = lane >> 5;
    int wg = blockIdx.x;                  // (b,h,t)
    int t = wg & 15, h = (wg >> 4) & 31, b = wg >> 9;
    const int s0 = (b * 32 + h) * 32;

    // stage A: 32 rows x 512 (32KB contiguous in aot) -> padded LDS (reg-staged)
    {
        const u16* src = aot + ((size_t)t * 4096 + s0) * 512;
        #pragma unroll
        for (int i = 0; i < 8; ++i){
            int flat = tid + 256 * i;          // 0..2047
            int row = flat >> 6, c16 = flat & 63;
            bf16x8 v = *(const bf16x8*)(src + (size_t)flat * 8);
            *(bf16x8*)(atile + row * 516 + c16 * 8) = v;
        }
    }
    __syncthreads();

    // wave's c-block range: 3/3/2/2
    const int nb_start = (wid < 2) ? wid * 3 : 6 + (wid - 2) * 2;
    const int nb_count = (wid < 2) ? 3 : 2;

    for (int j = 0; j < nb_count; ++j){
        const int nb = nb_start + j;
        f32x16 acc = (f32x16)Z16;
        const u16* wp = wof + ((size_t)(nb * 32) * 64 + lane) * 8;
        #pragma unroll
        for (int kt = 0; kt < 32; ++kt){
            bf16x8 af = *(const bf16x8*)(atile + l31 * 516 + kt * 16 + h32 * 8);
            bf16x8 bf = *(const bf16x8*)(wp + (size_t)kt * 512);
            acc = __builtin_amdgcn_mfma_f32_32x32x16_bf16(af, bf, acc, 0, 0, 0);
        }
        // C layout: col = l31 (c within block), row = (r&3)+8*(r>>2)+4*h32 (= w)
        float bias_v = bo[nb * 32 + l31];
        #pragma unroll
        for (int r = 0; r < 16; ++r){
            int row = (r & 3) + 8 * (r >> 2) + 4 * h32;
            otile[wid][l31 * 36 + row] = acc[r] + bias_v;
        }
        // residual + coalesced float4 write along w (same wave; compiler orders LDS RAW)
        int cl = lane >> 3;                   // 0..7
        int w4 = (lane & 7) * 4;
        #pragma unroll
        for (int ci = 0; ci < 4; ++ci){
            int c = ci * 8 + cl;
            size_t idx = ((size_t)(b * CC + nb * 32 + c) * TT + t) * 1024 + h * 32 + w4;
            f32x4 ov = *(const f32x4*)(&otile[wid][c * 36 + w4]);
            f32x4 xv = *(const f32x4*)(x + idx);
            *(f32x4*)(out + idx) = xv + ov;
        }
    }
}

extern "C" void kernel_launch(void* const* d_in, const int* in_sizes, int n_in,
                              void* d_out, int out_size, void* d_ws, size_t ws_size,
                              hipStream_t stream){
    const float* hid = (const float*)d_in[0];
    const float* lnw = (const float*)d_in[1];
    const float* lnb = (const float*)d_in[2];
    const float* Wq  = (const float*)d_in[3];
    const float* Wk  = (const float*)d_in[4];
    const float* Wv  = (const float*)d_in[5];
    const float* Wo  = (const float*)d_in[6];
    const float* bo  = (const float*)d_in[7];

    char* ws = (char*)d_ws;
    u16* wqkv = (u16*)ws;                                   // 960 frags * 512 = 491,520 elems
    u16* wo_f = wqkv + (size_t)960 * 512;                   // 320 frags * 512 = 163,840 elems
    u16* aot  = wo_f + 163840;                              // 16*4096*512 (67 MB), [t][sample][k]
    u16* xn   = aot + (size_t)TT * 4096 * INNER;            // 65536*320 (40 MB), 32-frag-major

    k_prep     <<<2368, 256, 0, stream>>>(Wq, Wk, Wv, Wo, lnw, lnb, hid, wqkv, wo_f, xn);
    k_attn     <<<256, 512, 0, stream>>>(xn, wqkv, aot);
    k_oproj_res<<<2048, 256, 0, stream>>>(aot, wo_f, bo, hid, (float*)d_out);
}